// Round 9
// baseline (630.353 us; speedup 1.0000x reference)
//
#include <hip/hip_runtime.h>
#include <math.h>

#define B_    16
#define H_    16
#define N_    4096
#define T_    8
#define DS_   256
#define DID_  128
#define L_    8
#define K_    32
#define DHID_ 1024
#define DSTEER_ 896
#define QH_   512
#define QO_   256
#define NW_   256   // B*H walkers
#define SLOTS_ 512  // chunk-slot space: 16 chunks x 32 slots
#define SCORE_SCALE 0.022097086912079608f  // 1/(8*sqrt(32))

struct KArgs {
    const float *s_in, *node_id, *ws_in, *token, *norm_w;
    const float *W1, *b1, *W2, *b2;
    const float *qw1, *qb1, *qw2, *qb2, *kw1, *kb1, *kw2, *kb2;
    const int *walker_pos, *plane_idx, *neighbors;
    float *out_motor, *out_s, *out_pos, *out_ws, *out_co, *out_vc, *out_lb;
    float *keys, *kh, *steer, *steerT, *h1p, *q1p, *c2p, *q2p, *mp_all;
    int *pos, *plane_order, *chunk_plane, *chunk_rows, *slot_of, *nchunks;
};

__device__ __forceinline__ float gelu_exact(float x) {
    return 0.5f * x * (1.0f + erff(x * 0.70710678118654752f));
}

#define FMA4(c, b, a) { c.x = fmaf(b.x, (a), c.x); c.y = fmaf(b.y, (a), c.y); \
                        c.z = fmaf(b.z, (a), c.z); c.w = fmaf(b.w, (a), c.w); }

__device__ __forceinline__ void gelu4(float4& v) {
    v.x = gelu_exact(v.x); v.y = gelu_exact(v.y);
    v.z = gelu_exact(v.z); v.w = gelu_exact(v.w);
}

// legacy 2-row x 4-col tile (used by keys / q-l2 paths)
__device__ __forceinline__ void rgemm_inner(
    const float* __restrict__ a0, const float* __restrict__ a1,
    const float* bp, int ldb, int K,
    float4& c0, float4& c1)
{
    for (int k = 0; k < K; k += 8) {
        const float4 a0l = *reinterpret_cast<const float4*>(a0 + k);
        const float4 a0h = *reinterpret_cast<const float4*>(a0 + k + 4);
        const float4 a1l = *reinterpret_cast<const float4*>(a1 + k);
        const float4 a1h = *reinterpret_cast<const float4*>(a1 + k + 4);
        const float* b8 = bp + (size_t)k * ldb;
#define KSTEP(o, av0, av1) { float4 bv = *reinterpret_cast<const float4*>(b8 + (size_t)(o) * ldb); \
                             FMA4(c0, bv, av0); FMA4(c1, bv, av1); }
        KSTEP(0, a0l.x, a1l.x)
        KSTEP(1, a0l.y, a1l.y)
        KSTEP(2, a0l.z, a1l.z)
        KSTEP(3, a0l.w, a1l.w)
        KSTEP(4, a0h.x, a1h.x)
        KSTEP(5, a0h.y, a1h.y)
        KSTEP(6, a0h.z, a1h.z)
        KSTEP(7, a0h.w, a1h.w)
#undef KSTEP
    }
}

// 8-row x 4-col register tile; A from global (rows stride lda), B from LDS
// (row stride ldb). 1 LDS b128 read per k -> 32 FMAs.
__device__ __forceinline__ void rgemm_8x4(
    const float* __restrict__ A, size_t lda,
    const float* Bs, int ldb, int K, float4 acc[8])
{
    for (int k = 0; k < K; k += 4) {
        float4 a[8];
#pragma unroll
        for (int r = 0; r < 8; ++r)
            a[r] = *reinterpret_cast<const float4*>(A + (size_t)r * lda + k);
        const float* b = Bs + k * ldb;
#pragma unroll
        for (int kk = 0; kk < 4; ++kk) {
            float4 bv = *reinterpret_cast<const float4*>(b + kk * ldb);
#pragma unroll
            for (int r = 0; r < 8; ++r) {
                float av = (kk == 0) ? a[r].x : (kk == 1) ? a[r].y
                         : (kk == 2) ? a[r].z : a[r].w;
                FMA4(acc[r], bv, av);
            }
        }
    }
}

// ---------------- setup1: tables (block 0) + keysA (blocks 1..1024) --------

__global__ __launch_bounds__(256) void setup1_kernel(KArgs a)
{
    int bid = blockIdx.x, tid = threadIdx.x;
    if (bid == 0) {
        a.pos[tid] = a.walker_pos[tid];
        a.mp_all[tid] = 0.f;
        __shared__ int cnt_s[8];
        __shared__ int cplane_s[16], cbase_s[16];
        __shared__ int nch_s;
        int wave = tid >> 6, lane = tid & 63;
        for (int pp = wave; pp < 8; pp += 4) {
            int base = 0;
            for (int c0 = 0; c0 < NW_; c0 += 64) {
                int w = c0 + lane;
                bool hit = (a.plane_idx[w] == pp);
                unsigned long long mask = __ballot(hit);
                if (hit) {
                    int rank = __popcll(mask & ((1ull << lane) - 1ull));
                    a.plane_order[pp * NW_ + base + rank] = w;
                }
                base += __popcll(mask);
            }
            if (lane == 0) cnt_s[pp] = base;
        }
        __syncthreads();
        if (tid == 0) {
            int nc = 0;
            for (int p = 0; p < 8; ++p)
                for (int s0 = 0; s0 < cnt_s[p]; s0 += 32) {
                    cplane_s[nc] = p; cbase_s[nc] = s0; ++nc;
                }
            *a.nchunks = nc;
            nch_s = nc;
        }
        __syncthreads();
        int nc = nch_s;
        for (int idx = tid; idx < 512; idx += 256) {
            int c = idx >> 5, i = idx & 31;
            int v = -1;
            if (c < nc) {
                int p = cplane_s[c];
                int r = cbase_s[c] + i;
                if (r < cnt_s[p]) v = a.plane_order[p * NW_ + r];
            }
            a.chunk_rows[c * 32 + i] = v;
            if (v >= 0) a.slot_of[v] = c * 32 + i;
            if (i == 0) a.chunk_plane[c] = (c < nc) ? cplane_s[c] : 0;
        }
    } else {
        // keysA: kh = gelu(node_id @ kw1 + kb1)
        int u = bid - 1;
        int rt = u >> 3, ct = u & 7;
        int tr = tid >> 4, tc = tid & 15;
        int row = rt * 32 + tr * 2, col = ct * 64 + tc * 4;
        const float* a0 = a.node_id + (size_t)row * DID_;
        float4 c0 = {0.f,0.f,0.f,0.f}, c1 = {0.f,0.f,0.f,0.f};
        rgemm_inner(a0, a0 + DID_, a.kw1 + col, QH_, DID_, c0, c1);
        float4 bv = *reinterpret_cast<const float4*>(a.kb1 + col);
        c0.x += bv.x; c0.y += bv.y; c0.z += bv.z; c0.w += bv.w;
        c1.x += bv.x; c1.y += bv.y; c1.z += bv.z; c1.w += bv.w;
        gelu4(c0); gelu4(c1);
        *reinterpret_cast<float4*>(a.kh + (size_t)row * QH_ + col) = c0;
        *reinterpret_cast<float4*>(a.kh + (size_t)(row + 1) * QH_ + col) = c1;
    }
}

// ---------------- steer body ----------------

__device__ void dev_steer(const KArgs& a, int w, int tid, int t) {
    int b = w >> 4;
    int p = a.pos[w];
    int slot = a.slot_of[w];
    float sc = a.out_s[((size_t)b * N_ + p) * DS_ + tid];
    float v = sc * sc;
    for (int off = 32; off > 0; off >>= 1) v += __shfl_down(v, off);
    __shared__ float red[4];
    if ((tid & 63) == 0) red[tid >> 6] = v;
    __syncthreads();
    float tot = red[0] + red[1] + red[2] + red[3];
    float r = rsqrtf(tot * (1.0f / DS_) + 1e-6f);
    float* st = a.steer + (size_t)w * DSTEER_;
    float v0 = sc * r * a.norm_w[tid];
    float v2 = a.out_ws[(size_t)w * DS_ + tid];
    float v3 = a.token[((size_t)b * T_ + t) * DS_ + tid];
    st[tid] = v0;
    st[384 + tid] = v2;
    st[640 + tid] = v3;
    a.steerT[(size_t)tid * SLOTS_ + slot] = v0;
    a.steerT[(size_t)(384 + tid) * SLOTS_ + slot] = v2;
    a.steerT[(size_t)(640 + tid) * SLOTS_ + slot] = v3;
    if (tid < 128) {
        float v1 = a.node_id[(size_t)p * DID_ + tid];
        st[256 + tid] = v1;
        a.steerT[(size_t)(256 + tid) * SLOTS_ + slot] = v1;
    }
}

// ---------------- setup2: keysB (512) + steer(0) (256) ----------------

__global__ __launch_bounds__(256) void setup2_kernel(KArgs a)
{
    int bid = blockIdx.x, tid = threadIdx.x;
    if (bid < 512) {
        int rt = bid >> 2, ct = bid & 3;
        int tr = tid >> 4, tc = tid & 15;
        int row = rt * 32 + tr * 2, col = ct * 64 + tc * 4;
        const float* a0 = a.kh + (size_t)row * QH_;
        float4 c0 = {0.f,0.f,0.f,0.f}, c1 = {0.f,0.f,0.f,0.f};
        rgemm_inner(a0, a0 + QH_, a.kw2 + col, QO_, QH_, c0, c1);
        float4 bv = *reinterpret_cast<const float4*>(a.kb2 + col);
        c0.x += bv.x; c0.y += bv.y; c0.z += bv.z; c0.w += bv.w;
        c1.x += bv.x; c1.y += bv.y; c1.z += bv.z; c1.w += bv.w;
        *reinterpret_cast<float4*>(a.keys + (size_t)row * QO_ + col) = c0;
        *reinterpret_cast<float4*>(a.keys + (size_t)(row + 1) * QO_ + col) = c1;
    } else {
        dev_steer(a, bid - 512, tid, 0);
    }
}

__global__ __launch_bounds__(256) void steer_kernel(KArgs a, int t)
{
    dev_steer(a, blockIdx.x, threadIdx.x, t);
}

// ---------------- layer1: 8x4 register tiles, LDS-staged B ----------------
// blocks 0..127: q hidden (256 walkers x 32 cols, K=112, kp-split 8)
// blocks 128..639: content hidden (256 J x 32 slots per block)

__global__ __launch_bounds__(256) void l1_kernel(KArgs a)
{
    __shared__ float bs[112 * 32];           // 14 KB
    int bid = blockIdx.x, tid = threadIdx.x;
    int tr = tid >> 3, tc = tid & 7;
    float4 acc[8];
#pragma unroll
    for (int r = 0; r < 8; ++r) acc[r] = make_float4(0.f, 0.f, 0.f, 0.f);

    if (bid < 128) {                         // q hidden
        int kp = bid & 7, ct = bid >> 3;     // 16 col-tiles of 32
        int col0 = ct * 32;
        // stage B = qw1[kp*112..+112][col0..+32]
#pragma unroll
        for (int i = 0; i < 4; ++i) {
            int idx = tid + i * 256;         // 896 float4s
            if (idx < 896) {
                int kk = idx >> 3, c4 = (idx & 7) << 2;
                *reinterpret_cast<float4*>(bs + kk * 32 + c4) =
                    *reinterpret_cast<const float4*>(a.qw1 + (size_t)(kp * 112 + kk) * QH_ + col0 + c4);
            }
        }
        __syncthreads();
        int w0 = tr * 8;                     // 8 walker rows
        rgemm_8x4(a.steer + (size_t)w0 * DSTEER_ + kp * 112, DSTEER_,
                  bs + tc * 4, 32, 112, acc);
        float* o = a.q1p + (size_t)kp * 131072;
        int col = col0 + tc * 4;
#pragma unroll
        for (int r = 0; r < 8; ++r)
            *reinterpret_cast<float4*>(o + (size_t)(w0 + r) * QH_ + col) = acc[r];
    } else {                                 // content hidden
        int b2 = bid - 128;
        int kp = b2 & 7, tile = b2 >> 3;     // 64 tiles: 16 chunks x 4 jt
        int c = tile >> 2, jt = tile & 3;
        if (c >= *a.nchunks) return;
        int p = a.chunk_plane[c];
        int J0 = jt * 256;
        // stage B = steerT[kp*112..+112][c*32..+32]
#pragma unroll
        for (int i = 0; i < 4; ++i) {
            int idx = tid + i * 256;         // 896 float4s
            if (idx < 896) {
                int kk = idx >> 3, s4 = (idx & 7) << 2;
                *reinterpret_cast<float4*>(bs + kk * 32 + s4) =
                    *reinterpret_cast<const float4*>(a.steerT + (size_t)(kp * 112 + kk) * SLOTS_ + c * 32 + s4);
            }
        }
        __syncthreads();
        int J = J0 + tr * 8;                 // 8 J rows
        rgemm_8x4(a.W1 + ((size_t)p * DHID_ + J) * DSTEER_ + kp * 112, DSTEER_,
                  bs + tc * 4, 32, 112, acc);
        float* o = a.h1p + (size_t)kp * 524288;
        int slot = c * 32 + tc * 4;
#pragma unroll
        for (int r = 0; r < 8; ++r)
            *reinterpret_cast<float4*>(o + (size_t)(J + r) * SLOTS_ + slot) = acc[r];
    }
}

// ---------------- layer2 fused: combine partials (+bias+gelu) in LDS, GEMM.
// blocks 0..255: q out (2x4 tiles, stage A from q1p)
// blocks 256..383: content out (8x4 tiles, stage B from h1p)

__global__ __launch_bounds__(256) void l2f_kernel(KArgs a)
{
    __shared__ float smem[4096];             // 16 KB
    int bid = blockIdx.x, tid = threadIdx.x;
    if (bid < 256) {
        int kp = bid & 7, tile = bid >> 3;
        int rt = tile >> 2, ct = tile & 3;
        int tr = tid >> 4, tc = tid & 15;
        int row0 = rt * 32, col = ct * 64 + tc * 4;
        float4 c0 = {0.f,0.f,0.f,0.f}, c1 = {0.f,0.f,0.f,0.f};
        // stage A[32][64] (pad to 72): A[r][k] = gelu(qb1 + sum_8 q1p)
#pragma unroll
        for (int i = 0; i < 2; ++i) {
            int idx = tid + i * 256;         // 512 float4s
            int r = idx >> 4, k4 = (idx & 15) << 2;
            size_t off = (size_t)(row0 + r) * QH_ + kp * 64 + k4;
            float4 acc = *reinterpret_cast<const float4*>(a.qb1 + kp * 64 + k4);
#pragma unroll
            for (int p8 = 0; p8 < 8; ++p8) {
                float4 v = *reinterpret_cast<const float4*>(a.q1p + (size_t)p8 * 131072 + off);
                acc.x += v.x; acc.y += v.y; acc.z += v.z; acc.w += v.w;
            }
            gelu4(acc);
            *reinterpret_cast<float4*>(smem + r * 72 + k4) = acc;
        }
        __syncthreads();
        const float* a0 = smem + (tr * 2) * 72;
        rgemm_inner(a0, a0 + 72, a.qw2 + (size_t)(kp * 64) * QO_ + col, QO_, 64, c0, c1);
        float* o = a.q2p + (size_t)kp * 65536;
        int row = row0 + tr * 2;
        *reinterpret_cast<float4*>(o + (size_t)row * QO_ + col) = c0;
        *reinterpret_cast<float4*>(o + (size_t)(row + 1) * QO_ + col) = c1;
    } else {
        int b2i = bid - 256;
        int kp = b2i & 7, c = b2i >> 3;      // 16 chunks
        if (c >= *a.nchunks) return;
        int p = a.chunk_plane[c];
        int tr = tid >> 3, tc = tid & 7;
        float4 acc8[8];
#pragma unroll
        for (int r = 0; r < 8; ++r) acc8[r] = make_float4(0.f, 0.f, 0.f, 0.f);
        // stage B[128][32]: B[kk][s] = gelu(b1[p][kq] + sum_8 h1p)
#pragma unroll
        for (int i = 0; i < 4; ++i) {
            int idx = tid + i * 256;         // 1024 float4s
            int kk = idx >> 3, s4 = (idx & 7) << 2;
            int kq = kp * 128 + kk;
            size_t off = (size_t)kq * SLOTS_ + c * 32 + s4;
            float bj = a.b1[p * DHID_ + kq];
            float4 acc = {bj, bj, bj, bj};
#pragma unroll
            for (int p8 = 0; p8 < 8; ++p8) {
                float4 v = *reinterpret_cast<const float4*>(a.h1p + (size_t)p8 * 524288 + off);
                acc.x += v.x; acc.y += v.y; acc.z += v.z; acc.w += v.w;
            }
            gelu4(acc);
            *reinterpret_cast<float4*>(smem + kk * 32 + s4) = acc;
        }
        __syncthreads();
        int J = tr * 8;                      // 8 J rows (J_tile = 256 = DS_)
        rgemm_8x4(a.W2 + ((size_t)p * DS_ + J) * DHID_ + kp * 128, DHID_,
                  smem + tc * 4, 32, 128, acc8);
        float* o = a.c2p + (size_t)kp * 131072;
        int slot = c * 32 + tc * 4;
#pragma unroll
        for (int r = 0; r < 8; ++r)
            *reinterpret_cast<float4*>(o + (size_t)(J + r) * SLOTS_ + slot) = acc8[r];
    }
}

// ---------------- score: sum l2 partials, softmax/argmax, state updates -----

__global__ __launch_bounds__(256) void score_kernel(KArgs a, int t)
{
    int w = blockIdx.x;
    int b = w >> 4;
    int tid = threadIdx.x;
    int pold = a.pos[w];
    int slot = a.slot_of[w];
    __shared__ float qv_s[256];
    __shared__ int nbr_s[32];
    __shared__ float part_s[8][32];
    __shared__ float sc_s[32];
    if (tid < 32) nbr_s[tid] = a.neighbors[(size_t)pold * K_ + tid];
    float qsum = a.qb2[tid];
#pragma unroll
    for (int kp = 0; kp < 8; ++kp) qsum += a.q2p[(size_t)kp * 65536 + (size_t)w * QO_ + tid];
    qv_s[tid] = qsum;
    float csum = a.b2[a.chunk_plane[slot >> 5] * DS_ + tid];
#pragma unroll
    for (int kp = 0; kp < 8; ++kp) csum += a.c2p[(size_t)kp * 131072 + (size_t)tid * SLOTS_ + slot];
    __syncthreads();
    int k = tid & 31, part = tid >> 5;
    int nk = nbr_s[k];
    const float* kp_ = a.keys + (size_t)nk * 256 + part * 32;
    const float* qp = qv_s + part * 32;
    float acc = 0.f;
#pragma unroll
    for (int i = 0; i < 32; i += 4) {
        float4 kv = *reinterpret_cast<const float4*>(kp_ + i);
        acc += kv.x * qp[i] + kv.y * qp[i+1] + kv.z * qp[i+2] + kv.w * qp[i+3];
    }
    part_s[part][k] = acc;
    __syncthreads();
    if (tid < 32) {
        float s = 0.f;
#pragma unroll
        for (int p8 = 0; p8 < 8; ++p8) s += part_s[p8][tid];
        sc_s[tid] = s * SCORE_SCALE;
    }
    __syncthreads();
    if (tid < 32) {
        float sv = sc_s[tid];
        float m = sv;
        for (int off = 1; off < 32; off <<= 1) m = fmaxf(m, __shfl_xor(m, off));
        float e = expf(sv - m);
        float ssum = e;
        for (int off = 1; off < 32; off <<= 1) ssum += __shfl_xor(ssum, off);
        float prob = e / ssum;
        atomicAdd(&a.mp_all[t * 32 + tid], prob);
        float bs = sv; int bi = tid;
        for (int off = 1; off < 32; off <<= 1) {
            float os = __shfl_xor(bs, off);
            int   oi = __shfl_xor(bi, off);
            if (os > bs || (os == bs && oi < bi)) { bs = os; bi = oi; }
        }
        if (tid == 0) {
            int next = nbr_s[bi];
            a.pos[w] = next;
            if (t == T_ - 1) a.out_pos[w] = (float)next;
            atomicAdd(&a.out_co[(size_t)pold * N_ + next], 1.0f);
            atomicAdd(&a.out_vc[next], 1.0f);
        }
    }
    atomicAdd(&a.out_s[((size_t)b * N_ + pold) * DS_ + tid], csum);
    float wn = a.out_ws[(size_t)w * DS_ + tid] + csum;
    a.out_ws[(size_t)w * DS_ + tid] = wn;
    atomicAdd(&a.out_motor[((size_t)b * T_ + t) * DS_ + tid], wn * (1.0f / H_));
}

__global__ __launch_bounds__(256) void final_kernel(KArgs a)
{
    int tid = threadIdx.x;
    float v = a.mp_all[tid] * (1.0f / 256.f);
    v = v * v;
    for (int off = 32; off > 0; off >>= 1) v += __shfl_down(v, off);
    __shared__ float red[4];
    if ((tid & 63) == 0) red[tid >> 6] = v;
    __syncthreads();
    if (tid == 0) a.out_lb[0] = (float)K_ * (red[0] + red[1] + red[2] + red[3]);
}

// ---------------- launch ----------------

extern "C" void kernel_launch(void* const* d_in, const int* in_sizes, int n_in,
                              void* d_out, int out_size, void* d_ws, size_t ws_size,
                              hipStream_t stream)
{
    KArgs a;
    a.s_in    = (const float*)d_in[0];
    a.node_id = (const float*)d_in[1];
    a.ws_in   = (const float*)d_in[2];
    a.token   = (const float*)d_in[3];
    a.norm_w  = (const float*)d_in[4];
    a.W1  = (const float*)d_in[5];
    a.b1  = (const float*)d_in[6];
    a.W2  = (const float*)d_in[7];
    a.b2  = (const float*)d_in[8];
    a.qw1 = (const float*)d_in[9];
    a.qb1 = (const float*)d_in[10];
    a.qw2 = (const float*)d_in[11];
    a.qb2 = (const float*)d_in[12];
    a.kw1 = (const float*)d_in[13];
    a.kb1 = (const float*)d_in[14];
    a.kw2 = (const float*)d_in[15];
    a.kb2 = (const float*)d_in[16];
    a.walker_pos = (const int*)d_in[17];
    a.plane_idx  = (const int*)d_in[18];
    a.neighbors  = (const int*)d_in[19];

    float* out = (float*)d_out;
    a.out_motor = out;                               // 32768
    a.out_s     = a.out_motor + 32768;               // 16777216
    a.out_pos   = a.out_s + (size_t)16777216;        // 256
    a.out_ws    = a.out_pos + 256;                   // 65536
    a.out_co    = a.out_ws + 65536;                  // 16777216
    a.out_vc    = a.out_co + (size_t)16777216;       // 4096
    a.out_lb    = a.out_vc + 4096;                   // 1

    float* ws = (float*)d_ws;
    a.keys   = ws;                                   // 1,048,576
    a.steer  = a.keys + 1048576;                     // 229,376
    a.steerT = a.steer + 229376;                     // 458,752
    a.h1p    = a.steerT + 458752;                    // 4,194,304
    a.kh     = a.h1p;                                // alias (setup only)
    a.q1p    = a.h1p + 4194304;                      // 1,048,576
    a.c2p    = a.q1p + 1048576;                      // 1,048,576
    a.q2p    = a.c2p + 1048576;                      // 524,288
    a.mp_all = a.q2p + 524288;                       // 256
    a.pos         = (int*)(a.mp_all + 256);          // 256
    a.plane_order = a.pos + 256;                     // 2048
    a.chunk_plane = a.plane_order + 2048;            // 16
    a.chunk_rows  = a.chunk_plane + 16;              // 512
    a.slot_of     = a.chunk_rows + 512;              // 256
    a.nchunks     = a.slot_of + 256;                 // 1

    // output init via runtime fill/copy kernels (measured ~6.9 TB/s on-chip)
    hipMemsetAsync(a.out_motor, 0, 32768 * sizeof(float), stream);
    hipMemsetAsync(a.out_co, 0, (size_t)(16777216 + 4096 + 1) * sizeof(float), stream);
    hipMemcpyAsync(a.out_s, a.s_in, (size_t)16777216 * sizeof(float),
                   hipMemcpyDeviceToDevice, stream);
    hipMemcpyAsync(a.out_ws, a.ws_in, (size_t)65536 * sizeof(float),
                   hipMemcpyDeviceToDevice, stream);

    setup1_kernel<<<1 + 1024, 256, 0, stream>>>(a);
    setup2_kernel<<<512 + 256, 256, 0, stream>>>(a);
    for (int t = 0; t < T_; ++t) {
        l1_kernel<<<128 + 512, 256, 0, stream>>>(a);
        l2f_kernel<<<256 + 128, 256, 0, stream>>>(a);
        score_kernel<<<256, 256, 0, stream>>>(a, t);
        if (t < T_ - 1) steer_kernel<<<256, 256, 0, stream>>>(a, t + 1);
    }
    final_kernel<<<1, 256, 0, stream>>>(a);
}

// Round 10
// 606.611 us; speedup vs baseline: 1.0391x; 1.0391x over previous
//
#include <hip/hip_runtime.h>
#include <math.h>

#define B_    16
#define H_    16
#define N_    4096
#define T_    8
#define DS_   256
#define DID_  128
#define L_    8
#define K_    32
#define DHID_ 1024
#define DSTEER_ 896
#define QH_   512
#define QO_   256
#define NW_   256   // B*H walkers
#define SLOTS_ 512  // chunk-slot space: 16 chunks x 32 slots
#define SCORE_SCALE 0.022097086912079608f  // 1/(8*sqrt(32))

struct KArgs {
    const float *s_in, *node_id, *ws_in, *token, *norm_w;
    const float *W1, *b1, *W2, *b2;
    const float *qw1, *qb1, *qw2, *qb2, *kw1, *kb1, *kw2, *kb2;
    const int *walker_pos, *plane_idx, *neighbors;
    float *out_motor, *out_s, *out_pos, *out_ws, *out_co, *out_vc, *out_lb;
    float *keys, *kh, *steer, *steerT, *h1p, *q1p, *c2p, *q2p, *mp_all;
    int *pos, *plane_order, *chunk_plane, *chunk_rows, *slot_of, *nchunks;
};

__device__ __forceinline__ float gelu_exact(float x) {
    return 0.5f * x * (1.0f + erff(x * 0.70710678118654752f));
}

#define FMA4(c, b, a) { c.x = fmaf(b.x, (a), c.x); c.y = fmaf(b.y, (a), c.y); \
                        c.z = fmaf(b.z, (a), c.z); c.w = fmaf(b.w, (a), c.w); }

__device__ __forceinline__ void gelu4(float4& v) {
    v.x = gelu_exact(v.x); v.y = gelu_exact(v.y);
    v.z = gelu_exact(v.z); v.w = gelu_exact(v.w);
}

// 2-row x 4-col tile (keys / q paths)
__device__ __forceinline__ void rgemm_inner(
    const float* __restrict__ a0, const float* __restrict__ a1,
    const float* bp, int ldb, int K,
    float4& c0, float4& c1)
{
    for (int k = 0; k < K; k += 8) {
        const float4 a0l = *reinterpret_cast<const float4*>(a0 + k);
        const float4 a0h = *reinterpret_cast<const float4*>(a0 + k + 4);
        const float4 a1l = *reinterpret_cast<const float4*>(a1 + k);
        const float4 a1h = *reinterpret_cast<const float4*>(a1 + k + 4);
        const float* b8 = bp + (size_t)k * ldb;
#define KSTEP(o, av0, av1) { float4 bv = *reinterpret_cast<const float4*>(b8 + (size_t)(o) * ldb); \
                             FMA4(c0, bv, av0); FMA4(c1, bv, av1); }
        KSTEP(0, a0l.x, a1l.x)
        KSTEP(1, a0l.y, a1l.y)
        KSTEP(2, a0l.z, a1l.z)
        KSTEP(3, a0l.w, a1l.w)
        KSTEP(4, a0h.x, a1h.x)
        KSTEP(5, a0h.y, a1h.y)
        KSTEP(6, a0h.z, a1h.z)
        KSTEP(7, a0h.w, a1h.w)
#undef KSTEP
    }
}

// 8-row x 4-col register tile; A from global (stride lda), B from LDS (ldb).
__device__ __forceinline__ void rgemm_8x4(
    const float* __restrict__ A, size_t lda,
    const float* Bs, int ldb, int K, float4 acc[8])
{
    for (int k = 0; k < K; k += 4) {
        float4 a[8];
#pragma unroll
        for (int r = 0; r < 8; ++r)
            a[r] = *reinterpret_cast<const float4*>(A + (size_t)r * lda + k);
        const float* b = Bs + k * ldb;
#pragma unroll
        for (int kk = 0; kk < 4; ++kk) {
            float4 bv = *reinterpret_cast<const float4*>(b + kk * ldb);
#pragma unroll
            for (int r = 0; r < 8; ++r) {
                float av = (kk == 0) ? a[r].x : (kk == 1) ? a[r].y
                         : (kk == 2) ? a[r].z : a[r].w;
                FMA4(acc[r], bv, av);
            }
        }
    }
}

// ---- setup1: biginit (0..4095) + tables (4096) + keysA (4097..5120) --------

__global__ __launch_bounds__(256) void setup1_kernel(KArgs a)
{
    int bid = blockIdx.x, tid = threadIdx.x;
    if (bid < 4096) {
        int gid = bid * 256 + tid, stride = 4096 * 256;
        const float4 z = {0.f, 0.f, 0.f, 0.f};
        float4* co4 = reinterpret_cast<float4*>(a.out_co);
        float4* s4o = reinterpret_cast<float4*>(a.out_s);
        const float4* s4i = reinterpret_cast<const float4*>(a.s_in);
        for (int i = gid; i < 4194304; i += stride) co4[i] = z;
        for (int i = gid; i < 4194304; i += stride) s4o[i] = s4i[i];
        float4* m4 = reinterpret_cast<float4*>(a.out_motor);
        for (int i = gid; i < 8192; i += stride) m4[i] = z;
        float4* w4o = reinterpret_cast<float4*>(a.out_ws);
        const float4* w4i = reinterpret_cast<const float4*>(a.ws_in);
        for (int i = gid; i < 16384; i += stride) w4o[i] = w4i[i];
        float4* v4 = reinterpret_cast<float4*>(a.out_vc);
        for (int i = gid; i < 1024; i += stride) v4[i] = z;
        if (gid == 0) a.out_lb[0] = 0.f;
    } else if (bid == 4096) {
        a.pos[tid] = a.walker_pos[tid];
        a.mp_all[tid] = 0.f;
        __shared__ int cnt_s[8];
        __shared__ int cplane_s[16], cbase_s[16];
        __shared__ int nch_s;
        int wave = tid >> 6, lane = tid & 63;
        for (int pp = wave; pp < 8; pp += 4) {
            int base = 0;
            for (int c0 = 0; c0 < NW_; c0 += 64) {
                int w = c0 + lane;
                bool hit = (a.plane_idx[w] == pp);
                unsigned long long mask = __ballot(hit);
                if (hit) {
                    int rank = __popcll(mask & ((1ull << lane) - 1ull));
                    a.plane_order[pp * NW_ + base + rank] = w;
                }
                base += __popcll(mask);
            }
            if (lane == 0) cnt_s[pp] = base;
        }
        __syncthreads();
        if (tid == 0) {
            int nc = 0;
            for (int p = 0; p < 8; ++p)
                for (int s0 = 0; s0 < cnt_s[p]; s0 += 32) {
                    cplane_s[nc] = p; cbase_s[nc] = s0; ++nc;
                }
            *a.nchunks = nc;
            nch_s = nc;
        }
        __syncthreads();
        int nc = nch_s;
        for (int idx = tid; idx < 512; idx += 256) {
            int c = idx >> 5, i = idx & 31;
            int v = -1;
            if (c < nc) {
                int p = cplane_s[c];
                int r = cbase_s[c] + i;
                if (r < cnt_s[p]) v = a.plane_order[p * NW_ + r];
            }
            a.chunk_rows[c * 32 + i] = v;
            if (v >= 0) a.slot_of[v] = c * 32 + i;
            if (i == 0) a.chunk_plane[c] = (c < nc) ? cplane_s[c] : 0;
        }
    } else {
        // keysA: kh = gelu(node_id @ kw1 + kb1)
        int u = bid - 4097;
        int rt = u >> 3, ct = u & 7;
        int tr = tid >> 4, tc = tid & 15;
        int row = rt * 32 + tr * 2, col = ct * 64 + tc * 4;
        const float* a0 = a.node_id + (size_t)row * DID_;
        float4 c0 = {0.f,0.f,0.f,0.f}, c1 = {0.f,0.f,0.f,0.f};
        rgemm_inner(a0, a0 + DID_, a.kw1 + col, QH_, DID_, c0, c1);
        float4 bv = *reinterpret_cast<const float4*>(a.kb1 + col);
        c0.x += bv.x; c0.y += bv.y; c0.z += bv.z; c0.w += bv.w;
        c1.x += bv.x; c1.y += bv.y; c1.z += bv.z; c1.w += bv.w;
        gelu4(c0); gelu4(c1);
        *reinterpret_cast<float4*>(a.kh + (size_t)row * QH_ + col) = c0;
        *reinterpret_cast<float4*>(a.kh + (size_t)(row + 1) * QH_ + col) = c1;
    }
}

// ---------------- steer body ----------------

__device__ void dev_steer(const KArgs& a, int w, int tid, int t) {
    int b = w >> 4;
    int p = a.pos[w];
    int slot = a.slot_of[w];
    float sc = a.out_s[((size_t)b * N_ + p) * DS_ + tid];
    float v = sc * sc;
    for (int off = 32; off > 0; off >>= 1) v += __shfl_down(v, off);
    __shared__ float red[4];
    if ((tid & 63) == 0) red[tid >> 6] = v;
    __syncthreads();
    float tot = red[0] + red[1] + red[2] + red[3];
    float r = rsqrtf(tot * (1.0f / DS_) + 1e-6f);
    float* st = a.steer + (size_t)w * DSTEER_;
    float v0 = sc * r * a.norm_w[tid];
    float v2 = a.out_ws[(size_t)w * DS_ + tid];
    float v3 = a.token[((size_t)b * T_ + t) * DS_ + tid];
    st[tid] = v0;
    st[384 + tid] = v2;
    st[640 + tid] = v3;
    a.steerT[(size_t)tid * SLOTS_ + slot] = v0;
    a.steerT[(size_t)(384 + tid) * SLOTS_ + slot] = v2;
    a.steerT[(size_t)(640 + tid) * SLOTS_ + slot] = v3;
    if (tid < 128) {
        float v1 = a.node_id[(size_t)p * DID_ + tid];
        st[256 + tid] = v1;
        a.steerT[(size_t)(256 + tid) * SLOTS_ + slot] = v1;
    }
}

// ---------------- setup2: keysB (512) + steer(0) (256) ----------------

__global__ __launch_bounds__(256) void setup2_kernel(KArgs a)
{
    int bid = blockIdx.x, tid = threadIdx.x;
    if (bid < 512) {
        int rt = bid >> 2, ct = bid & 3;
        int tr = tid >> 4, tc = tid & 15;
        int row = rt * 32 + tr * 2, col = ct * 64 + tc * 4;
        const float* a0 = a.kh + (size_t)row * QH_;
        float4 c0 = {0.f,0.f,0.f,0.f}, c1 = {0.f,0.f,0.f,0.f};
        rgemm_inner(a0, a0 + QH_, a.kw2 + col, QO_, QH_, c0, c1);
        float4 bv = *reinterpret_cast<const float4*>(a.kb2 + col);
        c0.x += bv.x; c0.y += bv.y; c0.z += bv.z; c0.w += bv.w;
        c1.x += bv.x; c1.y += bv.y; c1.z += bv.z; c1.w += bv.w;
        *reinterpret_cast<float4*>(a.keys + (size_t)row * QO_ + col) = c0;
        *reinterpret_cast<float4*>(a.keys + (size_t)(row + 1) * QO_ + col) = c1;
    } else {
        dev_steer(a, bid - 512, tid, 0);
    }
}

__global__ __launch_bounds__(256) void steer_kernel(KArgs a, int t)
{
    dev_steer(a, blockIdx.x, threadIdx.x, t);
}

// ---------------- layer1: 8x4 register tiles, LDS-staged B ----------------
// blocks 0..127: q hidden; 128..639: content hidden (256 J x 32 slots, K=112)

__global__ __launch_bounds__(256) void l1_kernel(KArgs a)
{
    __shared__ float bs[112 * 32];           // 14 KB
    int bid = blockIdx.x, tid = threadIdx.x;
    int tr = tid >> 3, tc = tid & 7;
    float4 acc[8];
#pragma unroll
    for (int r = 0; r < 8; ++r) acc[r] = make_float4(0.f, 0.f, 0.f, 0.f);

    if (bid < 128) {                         // q hidden
        int kp = bid & 7, ct = bid >> 3;     // 16 col-tiles of 32
        int col0 = ct * 32;
#pragma unroll
        for (int i = 0; i < 4; ++i) {
            int idx = tid + i * 256;         // 896 float4s
            if (idx < 896) {
                int kk = idx >> 3, c4 = (idx & 7) << 2;
                *reinterpret_cast<float4*>(bs + kk * 32 + c4) =
                    *reinterpret_cast<const float4*>(a.qw1 + (size_t)(kp * 112 + kk) * QH_ + col0 + c4);
            }
        }
        __syncthreads();
        int w0 = tr * 8;
        rgemm_8x4(a.steer + (size_t)w0 * DSTEER_ + kp * 112, DSTEER_,
                  bs + tc * 4, 32, 112, acc);
        float* o = a.q1p + (size_t)kp * 131072;
        int col = col0 + tc * 4;
#pragma unroll
        for (int r = 0; r < 8; ++r)
            *reinterpret_cast<float4*>(o + (size_t)(w0 + r) * QH_ + col) = acc[r];
    } else {                                 // content hidden
        int b2 = bid - 128;
        int kp = b2 & 7, tile = b2 >> 3;     // 64 tiles: 16 chunks x 4 jt
        int c = tile >> 2, jt = tile & 3;
        if (c >= *a.nchunks) return;
        int p = a.chunk_plane[c];
        int J0 = jt * 256;
#pragma unroll
        for (int i = 0; i < 4; ++i) {
            int idx = tid + i * 256;         // 896 float4s
            if (idx < 896) {
                int kk = idx >> 3, s4 = (idx & 7) << 2;
                *reinterpret_cast<float4*>(bs + kk * 32 + s4) =
                    *reinterpret_cast<const float4*>(a.steerT + (size_t)(kp * 112 + kk) * SLOTS_ + c * 32 + s4);
            }
        }
        __syncthreads();
        int J = J0 + tr * 8;
        rgemm_8x4(a.W1 + ((size_t)p * DHID_ + J) * DSTEER_ + kp * 112, DSTEER_,
                  bs + tc * 4, 32, 112, acc);
        float* o = a.h1p + (size_t)kp * 524288;
        int slot = c * 32 + tc * 4;
#pragma unroll
        for (int r = 0; r < 8; ++r)
            *reinterpret_cast<float4*>(o + (size_t)(J + r) * SLOTS_ + slot) = acc[r];
    }
}

// ---------------- layer2 fused: combine h1p/q1p partials (+bias+gelu) in LDS.
// blocks 0..255: q out (2x4 tiles, K-split x8)
// blocks 256..511: content out (8x4 tiles, K-split x16 -> 16 c2p partials)

__global__ __launch_bounds__(256) void l2f_kernel(KArgs a)
{
    __shared__ float smem[4096];             // 16 KB
    int bid = blockIdx.x, tid = threadIdx.x;
    if (bid < 256) {
        int kp = bid & 7, tile = bid >> 3;
        int rt = tile >> 2, ct = tile & 3;
        int tr = tid >> 4, tc = tid & 15;
        int row0 = rt * 32, col = ct * 64 + tc * 4;
        float4 c0 = {0.f,0.f,0.f,0.f}, c1 = {0.f,0.f,0.f,0.f};
        // stage A[32][64] (pad 72): A[r][k] = gelu(qb1 + sum_8 q1p)
#pragma unroll
        for (int i = 0; i < 2; ++i) {
            int idx = tid + i * 256;         // 512 float4s
            int r = idx >> 4, k4 = (idx & 15) << 2;
            size_t off = (size_t)(row0 + r) * QH_ + kp * 64 + k4;
            float4 acc = *reinterpret_cast<const float4*>(a.qb1 + kp * 64 + k4);
#pragma unroll
            for (int p8 = 0; p8 < 8; ++p8) {
                float4 v = *reinterpret_cast<const float4*>(a.q1p + (size_t)p8 * 131072 + off);
                acc.x += v.x; acc.y += v.y; acc.z += v.z; acc.w += v.w;
            }
            gelu4(acc);
            *reinterpret_cast<float4*>(smem + r * 72 + k4) = acc;
        }
        __syncthreads();
        const float* a0 = smem + (tr * 2) * 72;
        rgemm_inner(a0, a0 + 72, a.qw2 + (size_t)(kp * 64) * QO_ + col, QO_, 64, c0, c1);
        float* o = a.q2p + (size_t)kp * 65536;
        int row = row0 + tr * 2;
        *reinterpret_cast<float4*>(o + (size_t)row * QO_ + col) = c0;
        *reinterpret_cast<float4*>(o + (size_t)(row + 1) * QO_ + col) = c1;
    } else {
        int b2i = bid - 256;
        int kp2 = b2i & 15, c = b2i >> 4;    // K-split x16, 16 chunks
        if (c >= *a.nchunks) return;
        int p = a.chunk_plane[c];
        int tr = tid >> 3, tc = tid & 7;
        float4 acc8[8];
#pragma unroll
        for (int r = 0; r < 8; ++r) acc8[r] = make_float4(0.f, 0.f, 0.f, 0.f);
        // stage B[64][32]: B[kk][s] = gelu(b1[p][kq] + sum_8 h1p), kq = kp2*64+kk
#pragma unroll
        for (int i = 0; i < 2; ++i) {
            int idx = tid + i * 256;         // 512 float4s
            int kk = idx >> 3, s4 = (idx & 7) << 2;
            int kq = kp2 * 64 + kk;
            size_t off = (size_t)kq * SLOTS_ + c * 32 + s4;
            float bj = a.b1[p * DHID_ + kq];
            float4 acc = {bj, bj, bj, bj};
#pragma unroll
            for (int p8 = 0; p8 < 8; ++p8) {
                float4 v = *reinterpret_cast<const float4*>(a.h1p + (size_t)p8 * 524288 + off);
                acc.x += v.x; acc.y += v.y; acc.z += v.z; acc.w += v.w;
            }
            gelu4(acc);
            *reinterpret_cast<float4*>(smem + kk * 32 + s4) = acc;
        }
        __syncthreads();
        int J = tr * 8;                      // 256 J rows total
        rgemm_8x4(a.W2 + ((size_t)p * DS_ + J) * DHID_ + kp2 * 64, DHID_,
                  smem + tc * 4, 32, 64, acc8);
        float* o = a.c2p + (size_t)kp2 * 131072;
        int slot = c * 32 + tc * 4;
#pragma unroll
        for (int r = 0; r < 8; ++r)
            *reinterpret_cast<float4*>(o + (size_t)(J + r) * SLOTS_ + slot) = acc8[r];
    }
}

// ---------------- score: sum partials, softmax/argmax, state updates -----

__global__ __launch_bounds__(256) void score_kernel(KArgs a, int t)
{
    int w = blockIdx.x;
    int b = w >> 4;
    int tid = threadIdx.x;
    int pold = a.pos[w];
    int slot = a.slot_of[w];
    __shared__ float qv_s[256];
    __shared__ int nbr_s[32];
    __shared__ float part_s[8][32];
    __shared__ float sc_s[32];
    if (tid < 32) nbr_s[tid] = a.neighbors[(size_t)pold * K_ + tid];
    float qsum = a.qb2[tid];
#pragma unroll
    for (int kp = 0; kp < 8; ++kp) qsum += a.q2p[(size_t)kp * 65536 + (size_t)w * QO_ + tid];
    qv_s[tid] = qsum;
    float csum = a.b2[a.chunk_plane[slot >> 5] * DS_ + tid];
#pragma unroll
    for (int kp = 0; kp < 16; ++kp) csum += a.c2p[(size_t)kp * 131072 + (size_t)tid * SLOTS_ + slot];
    __syncthreads();
    int k = tid & 31, part = tid >> 5;
    int nk = nbr_s[k];
    const float* kp_ = a.keys + (size_t)nk * 256 + part * 32;
    const float* qp = qv_s + part * 32;
    float acc = 0.f;
#pragma unroll
    for (int i = 0; i < 32; i += 4) {
        float4 kv = *reinterpret_cast<const float4*>(kp_ + i);
        acc += kv.x * qp[i] + kv.y * qp[i+1] + kv.z * qp[i+2] + kv.w * qp[i+3];
    }
    part_s[part][k] = acc;
    __syncthreads();
    if (tid < 32) {
        float s = 0.f;
#pragma unroll
        for (int p8 = 0; p8 < 8; ++p8) s += part_s[p8][tid];
        sc_s[tid] = s * SCORE_SCALE;
    }
    __syncthreads();
    if (tid < 32) {
        float sv = sc_s[tid];
        float m = sv;
        for (int off = 1; off < 32; off <<= 1) m = fmaxf(m, __shfl_xor(m, off));
        float e = expf(sv - m);
        float ssum = e;
        for (int off = 1; off < 32; off <<= 1) ssum += __shfl_xor(ssum, off);
        float prob = e / ssum;
        atomicAdd(&a.mp_all[t * 32 + tid], prob);
        float bs = sv; int bi = tid;
        for (int off = 1; off < 32; off <<= 1) {
            float os = __shfl_xor(bs, off);
            int   oi = __shfl_xor(bi, off);
            if (os > bs || (os == bs && oi < bi)) { bs = os; bi = oi; }
        }
        if (tid == 0) {
            int next = nbr_s[bi];
            a.pos[w] = next;
            if (t == T_ - 1) a.out_pos[w] = (float)next;
            atomicAdd(&a.out_co[(size_t)pold * N_ + next], 1.0f);
            atomicAdd(&a.out_vc[next], 1.0f);
        }
    }
    atomicAdd(&a.out_s[((size_t)b * N_ + pold) * DS_ + tid], csum);
    float wn = a.out_ws[(size_t)w * DS_ + tid] + csum;
    a.out_ws[(size_t)w * DS_ + tid] = wn;
    atomicAdd(&a.out_motor[((size_t)b * T_ + t) * DS_ + tid], wn * (1.0f / H_));
}

__global__ __launch_bounds__(256) void final_kernel(KArgs a)
{
    int tid = threadIdx.x;
    float v = a.mp_all[tid] * (1.0f / 256.f);
    v = v * v;
    for (int off = 32; off > 0; off >>= 1) v += __shfl_down(v, off);
    __shared__ float red[4];
    if ((tid & 63) == 0) red[tid >> 6] = v;
    __syncthreads();
    if (tid == 0) a.out_lb[0] = (float)K_ * (red[0] + red[1] + red[2] + red[3]);
}

// ---------------- launch ----------------

extern "C" void kernel_launch(void* const* d_in, const int* in_sizes, int n_in,
                              void* d_out, int out_size, void* d_ws, size_t ws_size,
                              hipStream_t stream)
{
    KArgs a;
    a.s_in    = (const float*)d_in[0];
    a.node_id = (const float*)d_in[1];
    a.ws_in   = (const float*)d_in[2];
    a.token   = (const float*)d_in[3];
    a.norm_w  = (const float*)d_in[4];
    a.W1  = (const float*)d_in[5];
    a.b1  = (const float*)d_in[6];
    a.W2  = (const float*)d_in[7];
    a.b2  = (const float*)d_in[8];
    a.qw1 = (const float*)d_in[9];
    a.qb1 = (const float*)d_in[10];
    a.qw2 = (const float*)d_in[11];
    a.qb2 = (const float*)d_in[12];
    a.kw1 = (const float*)d_in[13];
    a.kb1 = (const float*)d_in[14];
    a.kw2 = (const float*)d_in[15];
    a.kb2 = (const float*)d_in[16];
    a.walker_pos = (const int*)d_in[17];
    a.plane_idx  = (const int*)d_in[18];
    a.neighbors  = (const int*)d_in[19];

    float* out = (float*)d_out;
    a.out_motor = out;                               // 32768
    a.out_s     = a.out_motor + 32768;               // 16777216
    a.out_pos   = a.out_s + (size_t)16777216;        // 256
    a.out_ws    = a.out_pos + 256;                   // 65536
    a.out_co    = a.out_ws + 65536;                  // 16777216
    a.out_vc    = a.out_co + (size_t)16777216;       // 4096
    a.out_lb    = a.out_vc + 4096;                   // 1

    float* ws = (float*)d_ws;
    a.keys   = ws;                                   // 1,048,576
    a.steer  = a.keys + 1048576;                     // 229,376
    a.steerT = a.steer + 229376;                     // 458,752
    a.h1p    = a.steerT + 458752;                    // 4,194,304
    a.kh     = a.h1p;                                // alias (setup only)
    a.q1p    = a.h1p + 4194304;                      // 1,048,576
    a.c2p    = a.q1p + 1048576;                      // 2,097,152 (16 partials)
    a.q2p    = a.c2p + 2097152;                      // 524,288
    a.mp_all = a.q2p + 524288;                       // 256
    a.pos         = (int*)(a.mp_all + 256);          // 256
    a.plane_order = a.pos + 256;                     // 2048
    a.chunk_plane = a.plane_order + 2048;            // 16
    a.chunk_rows  = a.chunk_plane + 16;              // 512
    a.slot_of     = a.chunk_rows + 512;              // 256
    a.nchunks     = a.slot_of + 256;                 // 1
    // total ~9.6M floats ~= 38.5 MB

    setup1_kernel<<<4096 + 1 + 1024, 256, 0, stream>>>(a);
    setup2_kernel<<<512 + 256, 256, 0, stream>>>(a);
    for (int t = 0; t < T_; ++t) {
        l1_kernel<<<128 + 512, 256, 0, stream>>>(a);
        l2f_kernel<<<256 + 256, 256, 0, stream>>>(a);
        score_kernel<<<256, 256, 0, stream>>>(a, t);
        if (t < T_ - 1) steer_kernel<<<256, 256, 0, stream>>>(a, t + 1);
    }
    final_kernel<<<1, 256, 0, stream>>>(a);
}

// Round 11
// 548.341 us; speedup vs baseline: 1.1496x; 1.1063x over previous
//
#include <hip/hip_runtime.h>
#include <math.h>

#define B_    16
#define H_    16
#define N_    4096
#define T_    8
#define DS_   256
#define DID_  128
#define L_    8
#define K_    32
#define DHID_ 1024
#define DSTEER_ 896
#define QH_   512
#define QO_   256
#define NW_   256   // B*H walkers
#define SLOTS_ 512  // chunk-slot space: 16 chunks x 32 slots
#define SCORE_SCALE 0.022097086912079608f  // 1/(8*sqrt(32))

struct KArgs {
    const float *s_in, *node_id, *ws_in, *token, *norm_w;
    const float *W1, *b1, *W2, *b2;
    const float *qw1, *qb1, *qw2, *qb2, *kw1, *kb1, *kw2, *kb2;
    const int *walker_pos, *plane_idx, *neighbors;
    float *out_motor, *out_s, *out_pos, *out_ws, *out_co, *out_vc, *out_lb;
    float *keys, *kh, *steer, *steerT, *h1p, *q1p, *c2p, *q2p, *mp_all;
    int *pos, *plane_order, *chunk_plane, *chunk_rows, *slot_of, *nchunks;
};

__device__ __forceinline__ float gelu_exact(float x) {
    return 0.5f * x * (1.0f + erff(x * 0.70710678118654752f));
}

#define FMA4(c, b, a) { c.x = fmaf(b.x, (a), c.x); c.y = fmaf(b.y, (a), c.y); \
                        c.z = fmaf(b.z, (a), c.z); c.w = fmaf(b.w, (a), c.w); }

__device__ __forceinline__ void gelu4(float4& v) {
    v.x = gelu_exact(v.x); v.y = gelu_exact(v.y);
    v.z = gelu_exact(v.z); v.w = gelu_exact(v.w);
}

// 2-row x 4-col register tile; B may live in LDS.
__device__ __forceinline__ void rgemm_inner(
    const float* __restrict__ a0, const float* __restrict__ a1,
    const float* bp, int ldb, int K,
    float4& c0, float4& c1)
{
    for (int k = 0; k < K; k += 8) {
        const float4 a0l = *reinterpret_cast<const float4*>(a0 + k);
        const float4 a0h = *reinterpret_cast<const float4*>(a0 + k + 4);
        const float4 a1l = *reinterpret_cast<const float4*>(a1 + k);
        const float4 a1h = *reinterpret_cast<const float4*>(a1 + k + 4);
        const float* b8 = bp + (size_t)k * ldb;
#define KSTEP(o, av0, av1) { float4 bv = *reinterpret_cast<const float4*>(b8 + (size_t)(o) * ldb); \
                             FMA4(c0, bv, av0); FMA4(c1, bv, av1); }
        KSTEP(0, a0l.x, a1l.x)
        KSTEP(1, a0l.y, a1l.y)
        KSTEP(2, a0l.z, a1l.z)
        KSTEP(3, a0l.w, a1l.w)
        KSTEP(4, a0h.x, a1h.x)
        KSTEP(5, a0h.y, a1h.y)
        KSTEP(6, a0h.z, a1h.z)
        KSTEP(7, a0h.w, a1h.w)
#undef KSTEP
    }
}

// ---- setup1: keysA (0..1023) + tables (1024) + biginit (1025..5120) --------
// keysA blocks first so compute overlaps the memory sweep.

__global__ __launch_bounds__(256) void setup1_kernel(KArgs a)
{
    int bid = blockIdx.x, tid = threadIdx.x;
    if (bid < 1024) {
        // keysA: kh = gelu(node_id @ kw1 + kb1)
        int u = bid;
        int rt = u >> 3, ct = u & 7;
        int tr = tid >> 4, tc = tid & 15;
        int row = rt * 32 + tr * 2, col = ct * 64 + tc * 4;
        const float* a0 = a.node_id + (size_t)row * DID_;
        float4 c0 = {0.f,0.f,0.f,0.f}, c1 = {0.f,0.f,0.f,0.f};
        rgemm_inner(a0, a0 + DID_, a.kw1 + col, QH_, DID_, c0, c1);
        float4 bv = *reinterpret_cast<const float4*>(a.kb1 + col);
        c0.x += bv.x; c0.y += bv.y; c0.z += bv.z; c0.w += bv.w;
        c1.x += bv.x; c1.y += bv.y; c1.z += bv.z; c1.w += bv.w;
        gelu4(c0); gelu4(c1);
        *reinterpret_cast<float4*>(a.kh + (size_t)row * QH_ + col) = c0;
        *reinterpret_cast<float4*>(a.kh + (size_t)(row + 1) * QH_ + col) = c1;
    } else if (bid == 1024) {
        a.pos[tid] = a.walker_pos[tid];
        a.mp_all[tid] = 0.f;
        __shared__ int cnt_s[8];
        __shared__ int cplane_s[16], cbase_s[16];
        __shared__ int nch_s;
        int wave = tid >> 6, lane = tid & 63;
        for (int pp = wave; pp < 8; pp += 4) {
            int base = 0;
            for (int c0 = 0; c0 < NW_; c0 += 64) {
                int w = c0 + lane;
                bool hit = (a.plane_idx[w] == pp);
                unsigned long long mask = __ballot(hit);
                if (hit) {
                    int rank = __popcll(mask & ((1ull << lane) - 1ull));
                    a.plane_order[pp * NW_ + base + rank] = w;
                }
                base += __popcll(mask);
            }
            if (lane == 0) cnt_s[pp] = base;
        }
        __syncthreads();
        if (tid == 0) {
            int nc = 0;
            for (int p = 0; p < 8; ++p)
                for (int s0 = 0; s0 < cnt_s[p]; s0 += 32) {
                    cplane_s[nc] = p; cbase_s[nc] = s0; ++nc;
                }
            *a.nchunks = nc;
            nch_s = nc;
        }
        __syncthreads();
        int nc = nch_s;
        for (int idx = tid; idx < 512; idx += 256) {
            int c = idx >> 5, i = idx & 31;
            int v = -1;
            if (c < nc) {
                int p = cplane_s[c];
                int r = cbase_s[c] + i;
                if (r < cnt_s[p]) v = a.plane_order[p * NW_ + r];
            }
            a.chunk_rows[c * 32 + i] = v;
            if (v >= 0) a.slot_of[v] = c * 32 + i;
            if (i == 0) a.chunk_plane[c] = (c < nc) ? cplane_s[c] : 0;
        }
    } else {
        int gid = (bid - 1025) * 256 + tid, stride = 4096 * 256;
        const float4 z = {0.f, 0.f, 0.f, 0.f};
        float4* co4 = reinterpret_cast<float4*>(a.out_co);
        float4* s4o = reinterpret_cast<float4*>(a.out_s);
        const float4* s4i = reinterpret_cast<const float4*>(a.s_in);
        for (int i = gid; i < 4194304; i += stride) co4[i] = z;
        for (int i = gid; i < 4194304; i += stride) s4o[i] = s4i[i];
        float4* m4 = reinterpret_cast<float4*>(a.out_motor);
        for (int i = gid; i < 8192; i += stride) m4[i] = z;
        float4* w4o = reinterpret_cast<float4*>(a.out_ws);
        const float4* w4i = reinterpret_cast<const float4*>(a.ws_in);
        for (int i = gid; i < 16384; i += stride) w4o[i] = w4i[i];
        float4* v4 = reinterpret_cast<float4*>(a.out_vc);
        for (int i = gid; i < 1024; i += stride) v4[i] = z;
        if (gid == 0) a.out_lb[0] = 0.f;
    }
}

// ---------------- steer body ----------------

__device__ void dev_steer(const KArgs& a, int w, int tid, int t) {
    int b = w >> 4;
    int p = a.pos[w];
    int slot = a.slot_of[w];
    float sc = a.out_s[((size_t)b * N_ + p) * DS_ + tid];
    float v = sc * sc;
    for (int off = 32; off > 0; off >>= 1) v += __shfl_down(v, off);
    __shared__ float red[4];
    if ((tid & 63) == 0) red[tid >> 6] = v;
    __syncthreads();
    float tot = red[0] + red[1] + red[2] + red[3];
    float r = rsqrtf(tot * (1.0f / DS_) + 1e-6f);
    float* st = a.steer + (size_t)w * DSTEER_;
    float v0 = sc * r * a.norm_w[tid];
    float v2 = a.out_ws[(size_t)w * DS_ + tid];
    float v3 = a.token[((size_t)b * T_ + t) * DS_ + tid];
    st[tid] = v0;
    st[384 + tid] = v2;
    st[640 + tid] = v3;
    a.steerT[(size_t)tid * SLOTS_ + slot] = v0;
    a.steerT[(size_t)(384 + tid) * SLOTS_ + slot] = v2;
    a.steerT[(size_t)(640 + tid) * SLOTS_ + slot] = v3;
    if (tid < 128) {
        float v1 = a.node_id[(size_t)p * DID_ + tid];
        st[256 + tid] = v1;
        a.steerT[(size_t)(256 + tid) * SLOTS_ + slot] = v1;
    }
}

// ---------------- setup2: keysB (512) + steer(0) (256) ----------------

__global__ __launch_bounds__(256) void setup2_kernel(KArgs a)
{
    int bid = blockIdx.x, tid = threadIdx.x;
    if (bid < 512) {
        int rt = bid >> 2, ct = bid & 3;
        int tr = tid >> 4, tc = tid & 15;
        int row = rt * 32 + tr * 2, col = ct * 64 + tc * 4;
        const float* a0 = a.kh + (size_t)row * QH_;
        float4 c0 = {0.f,0.f,0.f,0.f}, c1 = {0.f,0.f,0.f,0.f};
        rgemm_inner(a0, a0 + QH_, a.kw2 + col, QO_, QH_, c0, c1);
        float4 bv = *reinterpret_cast<const float4*>(a.kb2 + col);
        c0.x += bv.x; c0.y += bv.y; c0.z += bv.z; c0.w += bv.w;
        c1.x += bv.x; c1.y += bv.y; c1.z += bv.z; c1.w += bv.w;
        *reinterpret_cast<float4*>(a.keys + (size_t)row * QO_ + col) = c0;
        *reinterpret_cast<float4*>(a.keys + (size_t)(row + 1) * QO_ + col) = c1;
    } else {
        dev_steer(a, bid - 512, tid, 0);
    }
}

__global__ __launch_bounds__(256) void steer_kernel(KArgs a, int t)
{
    dev_steer(a, blockIdx.x, threadIdx.x, t);
}

// ---------------- layer1: K-split x8, LDS-staged B (r8 proven config) ------
// blocks 0..511: q hidden (32r x 64c, K=112); 512..2559: content hidden.

__global__ __launch_bounds__(256) void l1_kernel(KArgs a)
{
    __shared__ float bs[112 * 64];           // 28.7 KB (q); content uses 112*32
    int bid = blockIdx.x, tid = threadIdx.x;
    float4 c0 = {0.f,0.f,0.f,0.f}, c1 = {0.f,0.f,0.f,0.f};
    if (bid < 512) {
        int kp = bid & 7, tile = bid >> 3;
        int rt = tile >> 3, ct = tile & 7;
        int tr = tid >> 4, tc = tid & 15;
        int row = rt * 32 + tr * 2, col0 = ct * 64;
#pragma unroll
        for (int i = 0; i < 7; ++i) {
            int idx = tid + i * 256;             // 1792 float4s
            int kk = idx >> 4, c4 = (idx & 15) << 2;
            *reinterpret_cast<float4*>(bs + kk * 64 + c4) =
                *reinterpret_cast<const float4*>(a.qw1 + (size_t)(kp * 112 + kk) * QH_ + col0 + c4);
        }
        __syncthreads();
        const float* a0 = a.steer + (size_t)row * DSTEER_ + kp * 112;
        rgemm_inner(a0, a0 + DSTEER_, bs + tc * 4, 64, 112, c0, c1);
        float* o = a.q1p + (size_t)kp * 131072;
        int col = col0 + tc * 4;
        *reinterpret_cast<float4*>(o + (size_t)row * QH_ + col) = c0;
        *reinterpret_cast<float4*>(o + (size_t)(row + 1) * QH_ + col) = c1;
    } else {
        int b2 = bid - 512;
        int kp = b2 & 7, tile = b2 >> 3;
        int c = tile >> 4, jt = tile & 15;
        if (c >= *a.nchunks) return;
        int p = a.chunk_plane[c];
        int tr = tid >> 3, tc = tid & 7;
        int J = jt * 64 + tr * 2;
#pragma unroll
        for (int i = 0; i < 4; ++i) {
            int idx = tid + i * 256;             // 896 float4s
            if (idx < 896) {
                int kk = idx >> 3, s4 = (idx & 7) << 2;
                *reinterpret_cast<float4*>(bs + kk * 32 + s4) =
                    *reinterpret_cast<const float4*>(a.steerT + (size_t)(kp * 112 + kk) * SLOTS_ + c * 32 + s4);
            }
        }
        __syncthreads();
        const float* a0 = a.W1 + ((size_t)p * DHID_ + J) * DSTEER_ + kp * 112;
        rgemm_inner(a0, a0 + DSTEER_, bs + tc * 4, 32, 112, c0, c1);
        float* o = a.h1p + (size_t)kp * 524288;
        int slot = c * 32 + tc * 4;
        *reinterpret_cast<float4*>(o + (size_t)J * SLOTS_ + slot) = c0;
        *reinterpret_cast<float4*>(o + (size_t)(J + 1) * SLOTS_ + slot) = c1;
    }
}

// ---------------- layer2 fused (r8 proven config) ----------------
// blocks 0..255: q out (stage A from q1p); 256..767: content out (stage B).

__global__ __launch_bounds__(256) void l2f_kernel(KArgs a)
{
    __shared__ float smem[4096];             // 16 KB
    int bid = blockIdx.x, tid = threadIdx.x;
    if (bid < 256) {
        int kp = bid & 7, tile = bid >> 3;
        int rt = tile >> 2, ct = tile & 3;
        int tr = tid >> 4, tc = tid & 15;
        int row0 = rt * 32, col = ct * 64 + tc * 4;
        float4 c0 = {0.f,0.f,0.f,0.f}, c1 = {0.f,0.f,0.f,0.f};
        // stage A[32][64] (pad 72): A[r][k] = gelu(qb1 + sum_8 q1p)
#pragma unroll
        for (int i = 0; i < 2; ++i) {
            int idx = tid + i * 256;             // 512 float4s
            int r = idx >> 4, k4 = (idx & 15) << 2;
            size_t off = (size_t)(row0 + r) * QH_ + kp * 64 + k4;
            float4 acc = *reinterpret_cast<const float4*>(a.qb1 + kp * 64 + k4);
#pragma unroll
            for (int p8 = 0; p8 < 8; ++p8) {
                float4 v = *reinterpret_cast<const float4*>(a.q1p + (size_t)p8 * 131072 + off);
                acc.x += v.x; acc.y += v.y; acc.z += v.z; acc.w += v.w;
            }
            gelu4(acc);
            *reinterpret_cast<float4*>(smem + r * 72 + k4) = acc;
        }
        __syncthreads();
        const float* a0 = smem + (tr * 2) * 72;
        rgemm_inner(a0, a0 + 72, a.qw2 + (size_t)(kp * 64) * QO_ + col, QO_, 64, c0, c1);
        float* o = a.q2p + (size_t)kp * 65536;
        int row = row0 + tr * 2;
        *reinterpret_cast<float4*>(o + (size_t)row * QO_ + col) = c0;
        *reinterpret_cast<float4*>(o + (size_t)(row + 1) * QO_ + col) = c1;
    } else {
        int b2i = bid - 256;
        int kp = b2i & 7, tile = b2i >> 3;
        int c = tile >> 2, jt = tile & 3;
        if (c >= *a.nchunks) return;
        int p = a.chunk_plane[c];
        int tr = tid >> 3, tc = tid & 7;
        int J = jt * 64 + tr * 2;
        float4 c0 = {0.f,0.f,0.f,0.f}, c1 = {0.f,0.f,0.f,0.f};
        // stage B[128][32]: B[kk][s] = gelu(b1[p][kq] + sum_8 h1p)
#pragma unroll
        for (int i = 0; i < 4; ++i) {
            int idx = tid + i * 256;             // 1024 float4s
            int kk = idx >> 3, s4 = (idx & 7) << 2;
            int kq = kp * 128 + kk;
            size_t off = (size_t)kq * SLOTS_ + c * 32 + s4;
            float bj = a.b1[p * DHID_ + kq];
            float4 acc = {bj, bj, bj, bj};
#pragma unroll
            for (int p8 = 0; p8 < 8; ++p8) {
                float4 v = *reinterpret_cast<const float4*>(a.h1p + (size_t)p8 * 524288 + off);
                acc.x += v.x; acc.y += v.y; acc.z += v.z; acc.w += v.w;
            }
            gelu4(acc);
            *reinterpret_cast<float4*>(smem + kk * 32 + s4) = acc;
        }
        __syncthreads();
        const float* a0 = a.W2 + ((size_t)p * DS_ + J) * DHID_ + kp * 128;
        rgemm_inner(a0, a0 + DHID_, smem + tc * 4, 32, 128, c0, c1);
        float* o = a.c2p + (size_t)kp * 131072;
        int slot = c * 32 + tc * 4;
        *reinterpret_cast<float4*>(o + (size_t)J * SLOTS_ + slot) = c0;
        *reinterpret_cast<float4*>(o + (size_t)(J + 1) * SLOTS_ + slot) = c1;
    }
}

// ---------------- score: sum l2 partials, softmax/argmax, state updates -----

__global__ __launch_bounds__(256) void score_kernel(KArgs a, int t)
{
    int w = blockIdx.x;
    int b = w >> 4;
    int tid = threadIdx.x;
    int pold = a.pos[w];
    int slot = a.slot_of[w];
    __shared__ float qv_s[256];
    __shared__ int nbr_s[32];
    __shared__ float part_s[8][32];
    __shared__ float sc_s[32];
    if (tid < 32) nbr_s[tid] = a.neighbors[(size_t)pold * K_ + tid];
    float qsum = a.qb2[tid];
#pragma unroll
    for (int kp = 0; kp < 8; ++kp) qsum += a.q2p[(size_t)kp * 65536 + (size_t)w * QO_ + tid];
    qv_s[tid] = qsum;
    float csum = a.b2[a.chunk_plane[slot >> 5] * DS_ + tid];
#pragma unroll
    for (int kp = 0; kp < 8; ++kp) csum += a.c2p[(size_t)kp * 131072 + (size_t)tid * SLOTS_ + slot];
    __syncthreads();
    int k = tid & 31, part = tid >> 5;
    int nk = nbr_s[k];
    const float* kp_ = a.keys + (size_t)nk * 256 + part * 32;
    const float* qp = qv_s + part * 32;
    float acc = 0.f;
#pragma unroll
    for (int i = 0; i < 32; i += 4) {
        float4 kv = *reinterpret_cast<const float4*>(kp_ + i);
        acc += kv.x * qp[i] + kv.y * qp[i+1] + kv.z * qp[i+2] + kv.w * qp[i+3];
    }
    part_s[part][k] = acc;
    __syncthreads();
    if (tid < 32) {
        float s = 0.f;
#pragma unroll
        for (int p8 = 0; p8 < 8; ++p8) s += part_s[p8][tid];
        sc_s[tid] = s * SCORE_SCALE;
    }
    __syncthreads();
    if (tid < 32) {
        float sv = sc_s[tid];
        float m = sv;
        for (int off = 1; off < 32; off <<= 1) m = fmaxf(m, __shfl_xor(m, off));
        float e = expf(sv - m);
        float ssum = e;
        for (int off = 1; off < 32; off <<= 1) ssum += __shfl_xor(ssum, off);
        float prob = e / ssum;
        atomicAdd(&a.mp_all[t * 32 + tid], prob);
        float bs = sv; int bi = tid;
        for (int off = 1; off < 32; off <<= 1) {
            float os = __shfl_xor(bs, off);
            int   oi = __shfl_xor(bi, off);
            if (os > bs || (os == bs && oi < bi)) { bs = os; bi = oi; }
        }
        if (tid == 0) {
            int next = nbr_s[bi];
            a.pos[w] = next;
            if (t == T_ - 1) a.out_pos[w] = (float)next;
            atomicAdd(&a.out_co[(size_t)pold * N_ + next], 1.0f);
            atomicAdd(&a.out_vc[next], 1.0f);
        }
    }
    atomicAdd(&a.out_s[((size_t)b * N_ + pold) * DS_ + tid], csum);
    float wn = a.out_ws[(size_t)w * DS_ + tid] + csum;
    a.out_ws[(size_t)w * DS_ + tid] = wn;
    atomicAdd(&a.out_motor[((size_t)b * T_ + t) * DS_ + tid], wn * (1.0f / H_));
}

__global__ __launch_bounds__(256) void final_kernel(KArgs a)
{
    int tid = threadIdx.x;
    float v = a.mp_all[tid] * (1.0f / 256.f);
    v = v * v;
    for (int off = 32; off > 0; off >>= 1) v += __shfl_down(v, off);
    __shared__ float red[4];
    if ((tid & 63) == 0) red[tid >> 6] = v;
    __syncthreads();
    if (tid == 0) a.out_lb[0] = (float)K_ * (red[0] + red[1] + red[2] + red[3]);
}

// ---------------- launch ----------------

extern "C" void kernel_launch(void* const* d_in, const int* in_sizes, int n_in,
                              void* d_out, int out_size, void* d_ws, size_t ws_size,
                              hipStream_t stream)
{
    KArgs a;
    a.s_in    = (const float*)d_in[0];
    a.node_id = (const float*)d_in[1];
    a.ws_in   = (const float*)d_in[2];
    a.token   = (const float*)d_in[3];
    a.norm_w  = (const float*)d_in[4];
    a.W1  = (const float*)d_in[5];
    a.b1  = (const float*)d_in[6];
    a.W2  = (const float*)d_in[7];
    a.b2  = (const float*)d_in[8];
    a.qw1 = (const float*)d_in[9];
    a.qb1 = (const float*)d_in[10];
    a.qw2 = (const float*)d_in[11];
    a.qb2 = (const float*)d_in[12];
    a.kw1 = (const float*)d_in[13];
    a.kb1 = (const float*)d_in[14];
    a.kw2 = (const float*)d_in[15];
    a.kb2 = (const float*)d_in[16];
    a.walker_pos = (const int*)d_in[17];
    a.plane_idx  = (const int*)d_in[18];
    a.neighbors  = (const int*)d_in[19];

    float* out = (float*)d_out;
    a.out_motor = out;                               // 32768
    a.out_s     = a.out_motor + 32768;               // 16777216
    a.out_pos   = a.out_s + (size_t)16777216;        // 256
    a.out_ws    = a.out_pos + 256;                   // 65536
    a.out_co    = a.out_ws + 65536;                  // 16777216
    a.out_vc    = a.out_co + (size_t)16777216;       // 4096
    a.out_lb    = a.out_vc + 4096;                   // 1

    float* ws = (float*)d_ws;
    a.keys   = ws;                                   // 1,048,576
    a.steer  = a.keys + 1048576;                     // 229,376
    a.steerT = a.steer + 229376;                     // 458,752
    a.h1p    = a.steerT + 458752;                    // 4,194,304
    a.kh     = a.h1p;                                // alias (setup only)
    a.q1p    = a.h1p + 4194304;                      // 1,048,576
    a.c2p    = a.q1p + 1048576;                      // 1,048,576
    a.q2p    = a.c2p + 1048576;                      // 524,288
    a.mp_all = a.q2p + 524288;                       // 256
    a.pos         = (int*)(a.mp_all + 256);          // 256
    a.plane_order = a.pos + 256;                     // 2048
    a.chunk_plane = a.plane_order + 2048;            // 16
    a.chunk_rows  = a.chunk_plane + 16;              // 512
    a.slot_of     = a.chunk_rows + 512;              // 256
    a.nchunks     = a.slot_of + 256;                 // 1

    setup1_kernel<<<1024 + 1 + 4096, 256, 0, stream>>>(a);
    setup2_kernel<<<512 + 256, 256, 0, stream>>>(a);
    for (int t = 0; t < T_; ++t) {
        l1_kernel<<<2560, 256, 0, stream>>>(a);
        l2f_kernel<<<768, 256, 0, stream>>>(a);
        score_kernel<<<256, 256, 0, stream>>>(a, t);
        if (t < T_ - 1) steer_kernel<<<256, 256, 0, stream>>>(a, t + 1);
    }
    final_kernel<<<1, 256, 0, stream>>>(a);
}

// Round 12
// 512.809 us; speedup vs baseline: 1.2292x; 1.0693x over previous
//
#include <hip/hip_runtime.h>
#include <math.h>

#define B_    16
#define H_    16
#define N_    4096
#define T_    8
#define DS_   256
#define DID_  128
#define L_    8
#define K_    32
#define DHID_ 1024
#define DSTEER_ 896
#define QH_   512
#define QO_   256
#define NW_   256   // B*H walkers
#define SLOTS_ 512  // chunk-slot space: 16 chunks x 32 slots
#define SCORE_SCALE 0.022097086912079608f  // 1/(8*sqrt(32))

struct KArgs {
    const float *s_in, *node_id, *ws_in, *token, *norm_w;
    const float *W1, *b1, *W2, *b2;
    const float *qw1, *qb1, *qw2, *qb2, *kw1, *kb1, *kw2, *kb2;
    const int *walker_pos, *plane_idx, *neighbors;
    float *out_motor, *out_s, *out_pos, *out_ws, *out_co, *out_vc, *out_lb;
    float *keys, *kh, *steer, *steerT, *h1p, *q1p, *c2p, *q2p, *mp_all;
    int *pos, *plane_order, *chunk_plane, *chunk_rows, *slot_of, *nchunks;
};

__device__ __forceinline__ float gelu_exact(float x) {
    return 0.5f * x * (1.0f + erff(x * 0.70710678118654752f));
}

#define FMA4(c, b, a) { c.x = fmaf(b.x, (a), c.x); c.y = fmaf(b.y, (a), c.y); \
                        c.z = fmaf(b.z, (a), c.z); c.w = fmaf(b.w, (a), c.w); }

__device__ __forceinline__ void gelu4(float4& v) {
    v.x = gelu_exact(v.x); v.y = gelu_exact(v.y);
    v.z = gelu_exact(v.z); v.w = gelu_exact(v.w);
}

// 2-row x 4-col register tile; B may live in LDS.
__device__ __forceinline__ void rgemm_inner(
    const float* __restrict__ a0, const float* __restrict__ a1,
    const float* bp, int ldb, int K,
    float4& c0, float4& c1)
{
    for (int k = 0; k < K; k += 8) {
        const float4 a0l = *reinterpret_cast<const float4*>(a0 + k);
        const float4 a0h = *reinterpret_cast<const float4*>(a0 + k + 4);
        const float4 a1l = *reinterpret_cast<const float4*>(a1 + k);
        const float4 a1h = *reinterpret_cast<const float4*>(a1 + k + 4);
        const float* b8 = bp + (size_t)k * ldb;
#define KSTEP(o, av0, av1) { float4 bv = *reinterpret_cast<const float4*>(b8 + (size_t)(o) * ldb); \
                             FMA4(c0, bv, av0); FMA4(c1, bv, av1); }
        KSTEP(0, a0l.x, a1l.x)
        KSTEP(1, a0l.y, a1l.y)
        KSTEP(2, a0l.z, a1l.z)
        KSTEP(3, a0l.w, a1l.w)
        KSTEP(4, a0h.x, a1h.x)
        KSTEP(5, a0h.y, a1h.y)
        KSTEP(6, a0h.z, a1h.z)
        KSTEP(7, a0h.w, a1h.w)
#undef KSTEP
    }
}

// ---- setup1: keysA (0..1023) + tables (1024) + s/ws copy (1025..3072) ------
// co/vc/lb/motor zeroing is done by hipMemsetAsync (runtime fill ~6.9 TB/s).

__global__ __launch_bounds__(256) void setup1_kernel(KArgs a)
{
    int bid = blockIdx.x, tid = threadIdx.x;
    if (bid < 1024) {
        // keysA: kh = gelu(node_id @ kw1 + kb1)
        int u = bid;
        int rt = u >> 3, ct = u & 7;
        int tr = tid >> 4, tc = tid & 15;
        int row = rt * 32 + tr * 2, col = ct * 64 + tc * 4;
        const float* a0 = a.node_id + (size_t)row * DID_;
        float4 c0 = {0.f,0.f,0.f,0.f}, c1 = {0.f,0.f,0.f,0.f};
        rgemm_inner(a0, a0 + DID_, a.kw1 + col, QH_, DID_, c0, c1);
        float4 bv = *reinterpret_cast<const float4*>(a.kb1 + col);
        c0.x += bv.x; c0.y += bv.y; c0.z += bv.z; c0.w += bv.w;
        c1.x += bv.x; c1.y += bv.y; c1.z += bv.z; c1.w += bv.w;
        gelu4(c0); gelu4(c1);
        *reinterpret_cast<float4*>(a.kh + (size_t)row * QH_ + col) = c0;
        *reinterpret_cast<float4*>(a.kh + (size_t)(row + 1) * QH_ + col) = c1;
    } else if (bid == 1024) {
        a.pos[tid] = a.walker_pos[tid];
        a.mp_all[tid] = 0.f;
        __shared__ int cnt_s[8];
        __shared__ int cplane_s[16], cbase_s[16];
        __shared__ int nch_s;
        int wave = tid >> 6, lane = tid & 63;
        for (int pp = wave; pp < 8; pp += 4) {
            int base = 0;
            for (int c0 = 0; c0 < NW_; c0 += 64) {
                int w = c0 + lane;
                bool hit = (a.plane_idx[w] == pp);
                unsigned long long mask = __ballot(hit);
                if (hit) {
                    int rank = __popcll(mask & ((1ull << lane) - 1ull));
                    a.plane_order[pp * NW_ + base + rank] = w;
                }
                base += __popcll(mask);
            }
            if (lane == 0) cnt_s[pp] = base;
        }
        __syncthreads();
        if (tid == 0) {
            int nc = 0;
            for (int p = 0; p < 8; ++p)
                for (int s0 = 0; s0 < cnt_s[p]; s0 += 32) {
                    cplane_s[nc] = p; cbase_s[nc] = s0; ++nc;
                }
            *a.nchunks = nc;
            nch_s = nc;
        }
        __syncthreads();
        int nc = nch_s;
        for (int idx = tid; idx < 512; idx += 256) {
            int c = idx >> 5, i = idx & 31;
            int v = -1;
            if (c < nc) {
                int p = cplane_s[c];
                int r = cbase_s[c] + i;
                if (r < cnt_s[p]) v = a.plane_order[p * NW_ + r];
            }
            a.chunk_rows[c * 32 + i] = v;
            if (v >= 0) a.slot_of[v] = c * 32 + i;
            if (i == 0) a.chunk_plane[c] = (c < nc) ? cplane_s[c] : 0;
        }
    } else {
        // s / ws restore copy
        int gid = (bid - 1025) * 256 + tid, stride = 2048 * 256;
        float4* s4o = reinterpret_cast<float4*>(a.out_s);
        const float4* s4i = reinterpret_cast<const float4*>(a.s_in);
        for (int i = gid; i < 4194304; i += stride) s4o[i] = s4i[i];
        float4* w4o = reinterpret_cast<float4*>(a.out_ws);
        const float4* w4i = reinterpret_cast<const float4*>(a.ws_in);
        for (int i = gid; i < 16384; i += stride) w4o[i] = w4i[i];
    }
}

// ---------------- steer body ----------------

__device__ void dev_steer(const KArgs& a, int w, int tid, int t) {
    int b = w >> 4;
    int p = a.pos[w];
    int slot = a.slot_of[w];
    float sc = a.out_s[((size_t)b * N_ + p) * DS_ + tid];
    float v = sc * sc;
    for (int off = 32; off > 0; off >>= 1) v += __shfl_down(v, off);
    __shared__ float red[4];
    if ((tid & 63) == 0) red[tid >> 6] = v;
    __syncthreads();
    float tot = red[0] + red[1] + red[2] + red[3];
    float r = rsqrtf(tot * (1.0f / DS_) + 1e-6f);
    float* st = a.steer + (size_t)w * DSTEER_;
    float v0 = sc * r * a.norm_w[tid];
    float v2 = a.out_ws[(size_t)w * DS_ + tid];
    float v3 = a.token[((size_t)b * T_ + t) * DS_ + tid];
    st[tid] = v0;
    st[384 + tid] = v2;
    st[640 + tid] = v3;
    a.steerT[(size_t)tid * SLOTS_ + slot] = v0;
    a.steerT[(size_t)(384 + tid) * SLOTS_ + slot] = v2;
    a.steerT[(size_t)(640 + tid) * SLOTS_ + slot] = v3;
    if (tid < 128) {
        float v1 = a.node_id[(size_t)p * DID_ + tid];
        st[256 + tid] = v1;
        a.steerT[(size_t)(256 + tid) * SLOTS_ + slot] = v1;
    }
}

// ---------------- setup2: keysB (512) + steer(0) (256) ----------------

__global__ __launch_bounds__(256) void setup2_kernel(KArgs a)
{
    int bid = blockIdx.x, tid = threadIdx.x;
    if (bid < 512) {
        int rt = bid >> 2, ct = bid & 3;
        int tr = tid >> 4, tc = tid & 15;
        int row = rt * 32 + tr * 2, col = ct * 64 + tc * 4;
        const float* a0 = a.kh + (size_t)row * QH_;
        float4 c0 = {0.f,0.f,0.f,0.f}, c1 = {0.f,0.f,0.f,0.f};
        rgemm_inner(a0, a0 + QH_, a.kw2 + col, QO_, QH_, c0, c1);
        float4 bv = *reinterpret_cast<const float4*>(a.kb2 + col);
        c0.x += bv.x; c0.y += bv.y; c0.z += bv.z; c0.w += bv.w;
        c1.x += bv.x; c1.y += bv.y; c1.z += bv.z; c1.w += bv.w;
        *reinterpret_cast<float4*>(a.keys + (size_t)row * QO_ + col) = c0;
        *reinterpret_cast<float4*>(a.keys + (size_t)(row + 1) * QO_ + col) = c1;
    } else {
        dev_steer(a, bid - 512, tid, 0);
    }
}

__global__ __launch_bounds__(256) void steer_kernel(KArgs a, int t)
{
    dev_steer(a, blockIdx.x, threadIdx.x, t);
}

// ---------------- layer1: K-split x8, LDS-staged B (r8 proven config) ------
// blocks 0..511: q hidden (32r x 64c, K=112); 512..2559: content hidden.

__global__ __launch_bounds__(256) void l1_kernel(KArgs a)
{
    __shared__ float bs[112 * 64];           // 28.7 KB (q); content uses 112*32
    int bid = blockIdx.x, tid = threadIdx.x;
    float4 c0 = {0.f,0.f,0.f,0.f}, c1 = {0.f,0.f,0.f,0.f};
    if (bid < 512) {
        int kp = bid & 7, tile = bid >> 3;
        int rt = tile >> 3, ct = tile & 7;
        int tr = tid >> 4, tc = tid & 15;
        int row = rt * 32 + tr * 2, col0 = ct * 64;
#pragma unroll
        for (int i = 0; i < 7; ++i) {
            int idx = tid + i * 256;             // 1792 float4s
            int kk = idx >> 4, c4 = (idx & 15) << 2;
            *reinterpret_cast<float4*>(bs + kk * 64 + c4) =
                *reinterpret_cast<const float4*>(a.qw1 + (size_t)(kp * 112 + kk) * QH_ + col0 + c4);
        }
        __syncthreads();
        const float* a0 = a.steer + (size_t)row * DSTEER_ + kp * 112;
        rgemm_inner(a0, a0 + DSTEER_, bs + tc * 4, 64, 112, c0, c1);
        float* o = a.q1p + (size_t)kp * 131072;
        int col = col0 + tc * 4;
        *reinterpret_cast<float4*>(o + (size_t)row * QH_ + col) = c0;
        *reinterpret_cast<float4*>(o + (size_t)(row + 1) * QH_ + col) = c1;
    } else {
        int b2 = bid - 512;
        int kp = b2 & 7, tile = b2 >> 3;
        int c = tile >> 4, jt = tile & 15;
        if (c >= *a.nchunks) return;
        int p = a.chunk_plane[c];
        int tr = tid >> 3, tc = tid & 7;
        int J = jt * 64 + tr * 2;
#pragma unroll
        for (int i = 0; i < 4; ++i) {
            int idx = tid + i * 256;             // 896 float4s
            if (idx < 896) {
                int kk = idx >> 3, s4 = (idx & 7) << 2;
                *reinterpret_cast<float4*>(bs + kk * 32 + s4) =
                    *reinterpret_cast<const float4*>(a.steerT + (size_t)(kp * 112 + kk) * SLOTS_ + c * 32 + s4);
            }
        }
        __syncthreads();
        const float* a0 = a.W1 + ((size_t)p * DHID_ + J) * DSTEER_ + kp * 112;
        rgemm_inner(a0, a0 + DSTEER_, bs + tc * 4, 32, 112, c0, c1);
        float* o = a.h1p + (size_t)kp * 524288;
        int slot = c * 32 + tc * 4;
        *reinterpret_cast<float4*>(o + (size_t)J * SLOTS_ + slot) = c0;
        *reinterpret_cast<float4*>(o + (size_t)(J + 1) * SLOTS_ + slot) = c1;
    }
}

// ---------------- layer2 fused ----------------
// blocks 0..255: q out (stage A from q1p); 256..767: content out (stage B).
// Content writes c2p TRANSPOSED [kp][slot][J] via LDS bounce so score reads
// coalesced rows.

__global__ __launch_bounds__(256) void l2f_kernel(KArgs a)
{
    __shared__ float smem[4096];             // 16 KB
    int bid = blockIdx.x, tid = threadIdx.x;
    if (bid < 256) {
        int kp = bid & 7, tile = bid >> 3;
        int rt = tile >> 2, ct = tile & 3;
        int tr = tid >> 4, tc = tid & 15;
        int row0 = rt * 32, col = ct * 64 + tc * 4;
        float4 c0 = {0.f,0.f,0.f,0.f}, c1 = {0.f,0.f,0.f,0.f};
        // stage A[32][64] (pad 72): A[r][k] = gelu(qb1 + sum_8 q1p)
#pragma unroll
        for (int i = 0; i < 2; ++i) {
            int idx = tid + i * 256;             // 512 float4s
            int r = idx >> 4, k4 = (idx & 15) << 2;
            size_t off = (size_t)(row0 + r) * QH_ + kp * 64 + k4;
            float4 acc = *reinterpret_cast<const float4*>(a.qb1 + kp * 64 + k4);
#pragma unroll
            for (int p8 = 0; p8 < 8; ++p8) {
                float4 v = *reinterpret_cast<const float4*>(a.q1p + (size_t)p8 * 131072 + off);
                acc.x += v.x; acc.y += v.y; acc.z += v.z; acc.w += v.w;
            }
            gelu4(acc);
            *reinterpret_cast<float4*>(smem + r * 72 + k4) = acc;
        }
        __syncthreads();
        const float* a0 = smem + (tr * 2) * 72;
        rgemm_inner(a0, a0 + 72, a.qw2 + (size_t)(kp * 64) * QO_ + col, QO_, 64, c0, c1);
        float* o = a.q2p + (size_t)kp * 65536;
        int row = row0 + tr * 2;
        *reinterpret_cast<float4*>(o + (size_t)row * QO_ + col) = c0;
        *reinterpret_cast<float4*>(o + (size_t)(row + 1) * QO_ + col) = c1;
    } else {
        int b2i = bid - 256;
        int kp = b2i & 7, tile = b2i >> 3;
        int c = tile >> 2, jt = tile & 3;
        if (c >= *a.nchunks) return;
        int p = a.chunk_plane[c];
        int tr = tid >> 3, tc = tid & 7;
        int J = jt * 64 + tr * 2;
        float4 c0 = {0.f,0.f,0.f,0.f}, c1 = {0.f,0.f,0.f,0.f};
        // stage B[128][32]: B[kk][s] = gelu(b1[p][kq] + sum_8 h1p)
#pragma unroll
        for (int i = 0; i < 4; ++i) {
            int idx = tid + i * 256;             // 1024 float4s
            int kk = idx >> 3, s4 = (idx & 7) << 2;
            int kq = kp * 128 + kk;
            size_t off = (size_t)kq * SLOTS_ + c * 32 + s4;
            float bj = a.b1[p * DHID_ + kq];
            float4 acc = {bj, bj, bj, bj};
#pragma unroll
            for (int p8 = 0; p8 < 8; ++p8) {
                float4 v = *reinterpret_cast<const float4*>(a.h1p + (size_t)p8 * 524288 + off);
                acc.x += v.x; acc.y += v.y; acc.z += v.z; acc.w += v.w;
            }
            gelu4(acc);
            *reinterpret_cast<float4*>(smem + kk * 32 + s4) = acc;
        }
        __syncthreads();
        const float* a0 = a.W2 + ((size_t)p * DS_ + J) * DHID_ + kp * 128;
        rgemm_inner(a0, a0 + DHID_, smem + tc * 4, 32, 128, c0, c1);
        // bounce acc through LDS -> write c2p transposed [slot][J] coalesced
        __syncthreads();                 // B-stage no longer needed
        int jl = tr * 2;
        smem[(tc*4+0)*66 + jl]     = c0.x;
        smem[(tc*4+1)*66 + jl]     = c0.y;
        smem[(tc*4+2)*66 + jl]     = c0.z;
        smem[(tc*4+3)*66 + jl]     = c0.w;
        smem[(tc*4+0)*66 + jl + 1] = c1.x;
        smem[(tc*4+1)*66 + jl + 1] = c1.y;
        smem[(tc*4+2)*66 + jl + 1] = c1.z;
        smem[(tc*4+3)*66 + jl + 1] = c1.w;
        __syncthreads();
        float* o = a.c2p + (size_t)kp * 131072;
#pragma unroll
        for (int i = 0; i < 2; ++i) {
            int f4i = tid + i * 256;     // 512 f4s: 32 slots x 16 f4-of-J
            int sl = f4i >> 4, j4 = (f4i & 15) << 2;
            float4 v;
            v.x = smem[sl * 66 + j4 + 0];
            v.y = smem[sl * 66 + j4 + 1];
            v.z = smem[sl * 66 + j4 + 2];
            v.w = smem[sl * 66 + j4 + 3];
            *reinterpret_cast<float4*>(o + (size_t)(c * 32 + sl) * 256 + jt * 64 + j4) = v;
        }
    }
}

// ---------------- score: sum l2 partials, softmax/argmax, state updates -----

__global__ __launch_bounds__(256) void score_kernel(KArgs a, int t)
{
    int w = blockIdx.x;
    int b = w >> 4;
    int tid = threadIdx.x;
    int pold = a.pos[w];
    int slot = a.slot_of[w];
    __shared__ float qv_s[256];
    __shared__ int nbr_s[32];
    __shared__ float part_s[8][32];
    __shared__ float sc_s[32];
    if (tid < 32) nbr_s[tid] = a.neighbors[(size_t)pold * K_ + tid];
    float qsum = a.qb2[tid];
#pragma unroll
    for (int kp = 0; kp < 8; ++kp) qsum += a.q2p[(size_t)kp * 65536 + (size_t)w * QO_ + tid];
    qv_s[tid] = qsum;
    // c2p transposed: [kp][slot][J] -> coalesced row read
    float csum = a.b2[a.chunk_plane[slot >> 5] * DS_ + tid];
#pragma unroll
    for (int kp = 0; kp < 8; ++kp) csum += a.c2p[(size_t)kp * 131072 + (size_t)slot * 256 + tid];
    __syncthreads();
    int k = tid & 31, part = tid >> 5;
    int nk = nbr_s[k];
    const float* kp_ = a.keys + (size_t)nk * 256 + part * 32;
    const float* qp = qv_s + part * 32;
    float acc = 0.f;
#pragma unroll
    for (int i = 0; i < 32; i += 4) {
        float4 kv = *reinterpret_cast<const float4*>(kp_ + i);
        acc += kv.x * qp[i] + kv.y * qp[i+1] + kv.z * qp[i+2] + kv.w * qp[i+3];
    }
    part_s[part][k] = acc;
    __syncthreads();
    if (tid < 32) {
        float s = 0.f;
#pragma unroll
        for (int p8 = 0; p8 < 8; ++p8) s += part_s[p8][tid];
        sc_s[tid] = s * SCORE_SCALE;
    }
    __syncthreads();
    if (tid < 32) {
        float sv = sc_s[tid];
        float m = sv;
        for (int off = 1; off < 32; off <<= 1) m = fmaxf(m, __shfl_xor(m, off));
        float e = expf(sv - m);
        float ssum = e;
        for (int off = 1; off < 32; off <<= 1) ssum += __shfl_xor(ssum, off);
        float prob = e / ssum;
        atomicAdd(&a.mp_all[t * 32 + tid], prob);
        float bs = sv; int bi = tid;
        for (int off = 1; off < 32; off <<= 1) {
            float os = __shfl_xor(bs, off);
            int   oi = __shfl_xor(bi, off);
            if (os > bs || (os == bs && oi < bi)) { bs = os; bi = oi; }
        }
        if (tid == 0) {
            int next = nbr_s[bi];
            a.pos[w] = next;
            if (t == T_ - 1) a.out_pos[w] = (float)next;
            atomicAdd(&a.out_co[(size_t)pold * N_ + next], 1.0f);
            atomicAdd(&a.out_vc[next], 1.0f);
        }
    }
    atomicAdd(&a.out_s[((size_t)b * N_ + pold) * DS_ + tid], csum);
    float wn = a.out_ws[(size_t)w * DS_ + tid] + csum;
    a.out_ws[(size_t)w * DS_ + tid] = wn;
    atomicAdd(&a.out_motor[((size_t)b * T_ + t) * DS_ + tid], wn * (1.0f / H_));
}

__global__ __launch_bounds__(256) void final_kernel(KArgs a)
{
    int tid = threadIdx.x;
    float v = a.mp_all[tid] * (1.0f / 256.f);
    v = v * v;
    for (int off = 32; off > 0; off >>= 1) v += __shfl_down(v, off);
    __shared__ float red[4];
    if ((tid & 63) == 0) red[tid >> 6] = v;
    __syncthreads();
    if (tid == 0) a.out_lb[0] = (float)K_ * (red[0] + red[1] + red[2] + red[3]);
}

// ---------------- launch ----------------

extern "C" void kernel_launch(void* const* d_in, const int* in_sizes, int n_in,
                              void* d_out, int out_size, void* d_ws, size_t ws_size,
                              hipStream_t stream)
{
    KArgs a;
    a.s_in    = (const float*)d_in[0];
    a.node_id = (const float*)d_in[1];
    a.ws_in   = (const float*)d_in[2];
    a.token   = (const float*)d_in[3];
    a.norm_w  = (const float*)d_in[4];
    a.W1  = (const float*)d_in[5];
    a.b1  = (const float*)d_in[6];
    a.W2  = (const float*)d_in[7];
    a.b2  = (const float*)d_in[8];
    a.qw1 = (const float*)d_in[9];
    a.qb1 = (const float*)d_in[10];
    a.qw2 = (const float*)d_in[11];
    a.qb2 = (const float*)d_in[12];
    a.kw1 = (const float*)d_in[13];
    a.kb1 = (const float*)d_in[14];
    a.kw2 = (const float*)d_in[15];
    a.kb2 = (const float*)d_in[16];
    a.walker_pos = (const int*)d_in[17];
    a.plane_idx  = (const int*)d_in[18];
    a.neighbors  = (const int*)d_in[19];

    float* out = (float*)d_out;
    a.out_motor = out;                               // 32768
    a.out_s     = a.out_motor + 32768;               // 16777216
    a.out_pos   = a.out_s + (size_t)16777216;        // 256
    a.out_ws    = a.out_pos + 256;                   // 65536
    a.out_co    = a.out_ws + 65536;                  // 16777216
    a.out_vc    = a.out_co + (size_t)16777216;       // 4096
    a.out_lb    = a.out_vc + 4096;                   // 1

    float* ws = (float*)d_ws;
    a.keys   = ws;                                   // 1,048,576
    a.steer  = a.keys + 1048576;                     // 229,376
    a.steerT = a.steer + 229376;                     // 458,752
    a.h1p    = a.steerT + 458752;                    // 4,194,304
    a.kh     = a.h1p;                                // alias (setup only)
    a.q1p    = a.h1p + 4194304;                      // 1,048,576
    a.c2p    = a.q1p + 1048576;                      // 1,048,576 (transposed)
    a.q2p    = a.c2p + 1048576;                      // 524,288
    a.mp_all = a.q2p + 524288;                       // 256
    a.pos         = (int*)(a.mp_all + 256);          // 256
    a.plane_order = a.pos + 256;                     // 2048
    a.chunk_plane = a.plane_order + 2048;            // 16
    a.chunk_rows  = a.chunk_plane + 16;              // 512
    a.slot_of     = a.chunk_rows + 512;              // 256
    a.nchunks     = a.slot_of + 256;                 // 1

    // zero outputs via runtime fill path (~6.9 TB/s measured on this chip)
    hipMemsetAsync(a.out_motor, 0, 32768 * sizeof(float), stream);
    hipMemsetAsync(a.out_co, 0, (size_t)(16777216 + 4096 + 1) * sizeof(float), stream);

    setup1_kernel<<<1024 + 1 + 2048, 256, 0, stream>>>(a);
    setup2_kernel<<<512 + 256, 256, 0, stream>>>(a);
    for (int t = 0; t < T_; ++t) {
        l1_kernel<<<2560, 256, 0, stream>>>(a);
        l2f_kernel<<<768, 256, 0, stream>>>(a);
        score_kernel<<<256, 256, 0, stream>>>(a, t);
        if (t < T_ - 1) steer_kernel<<<256, 256, 0, stream>>>(a, t + 1);
    }
    final_kernel<<<1, 256, 0, stream>>>(a);
}

// Round 13
// 502.203 us; speedup vs baseline: 1.2552x; 1.0211x over previous
//
#include <hip/hip_runtime.h>
#include <math.h>

#define B_    16
#define H_    16
#define N_    4096
#define T_    8
#define DS_   256
#define DID_  128
#define L_    8
#define K_    32
#define DHID_ 1024
#define DSTEER_ 896
#define QH_   512
#define QO_   256
#define NW_   256   // B*H walkers
#define SLOTS_ 512  // chunk-slot space: 16 chunks x 32 slots
#define SCORE_SCALE 0.022097086912079608f  // 1/(8*sqrt(32))

struct KArgs {
    const float *s_in, *node_id, *ws_in, *token, *norm_w;
    const float *W1, *b1, *W2, *b2;
    const float *qw1, *qb1, *qw2, *qb2, *kw1, *kb1, *kw2, *kb2;
    const int *walker_pos, *plane_idx, *neighbors;
    float *out_motor, *out_s, *out_pos, *out_ws, *out_co, *out_vc, *out_lb;
    float *keys, *kh, *steer, *steerT, *h1p, *q1p, *c2p, *q2p, *mp_all;
    int *pos, *plane_order, *chunk_plane, *chunk_rows, *slot_of, *nchunks;
};

__device__ __forceinline__ float gelu_exact(float x) {
    return 0.5f * x * (1.0f + erff(x * 0.70710678118654752f));
}

#define FMA4(c, b, a) { c.x = fmaf(b.x, (a), c.x); c.y = fmaf(b.y, (a), c.y); \
                        c.z = fmaf(b.z, (a), c.z); c.w = fmaf(b.w, (a), c.w); }

__device__ __forceinline__ void gelu4(float4& v) {
    v.x = gelu_exact(v.x); v.y = gelu_exact(v.y);
    v.z = gelu_exact(v.z); v.w = gelu_exact(v.w);
}

// 2-row x 4-col register tile; B may live in LDS.
__device__ __forceinline__ void rgemm_inner(
    const float* __restrict__ a0, const float* __restrict__ a1,
    const float* bp, int ldb, int K,
    float4& c0, float4& c1)
{
    for (int k = 0; k < K; k += 8) {
        const float4 a0l = *reinterpret_cast<const float4*>(a0 + k);
        const float4 a0h = *reinterpret_cast<const float4*>(a0 + k + 4);
        const float4 a1l = *reinterpret_cast<const float4*>(a1 + k);
        const float4 a1h = *reinterpret_cast<const float4*>(a1 + k + 4);
        const float* b8 = bp + (size_t)k * ldb;
#define KSTEP(o, av0, av1) { float4 bv = *reinterpret_cast<const float4*>(b8 + (size_t)(o) * ldb); \
                             FMA4(c0, bv, av0); FMA4(c1, bv, av1); }
        KSTEP(0, a0l.x, a1l.x)
        KSTEP(1, a0l.y, a1l.y)
        KSTEP(2, a0l.z, a1l.z)
        KSTEP(3, a0l.w, a1l.w)
        KSTEP(4, a0h.x, a1h.x)
        KSTEP(5, a0h.y, a1h.y)
        KSTEP(6, a0h.z, a1h.z)
        KSTEP(7, a0h.w, a1h.w)
#undef KSTEP
    }
}

// ---- setup1: keysA (0..1023) + tables (1024) + s/ws copy (1025..3072) ------

__global__ __launch_bounds__(256) void setup1_kernel(KArgs a)
{
    int bid = blockIdx.x, tid = threadIdx.x;
    if (bid < 1024) {
        // keysA: kh = gelu(node_id @ kw1 + kb1)
        int u = bid;
        int rt = u >> 3, ct = u & 7;
        int tr = tid >> 4, tc = tid & 15;
        int row = rt * 32 + tr * 2, col = ct * 64 + tc * 4;
        const float* a0 = a.node_id + (size_t)row * DID_;
        float4 c0 = {0.f,0.f,0.f,0.f}, c1 = {0.f,0.f,0.f,0.f};
        rgemm_inner(a0, a0 + DID_, a.kw1 + col, QH_, DID_, c0, c1);
        float4 bv = *reinterpret_cast<const float4*>(a.kb1 + col);
        c0.x += bv.x; c0.y += bv.y; c0.z += bv.z; c0.w += bv.w;
        c1.x += bv.x; c1.y += bv.y; c1.z += bv.z; c1.w += bv.w;
        gelu4(c0); gelu4(c1);
        *reinterpret_cast<float4*>(a.kh + (size_t)row * QH_ + col) = c0;
        *reinterpret_cast<float4*>(a.kh + (size_t)(row + 1) * QH_ + col) = c1;
    } else if (bid == 1024) {
        a.pos[tid] = a.walker_pos[tid];
        a.mp_all[tid] = 0.f;
        __shared__ int cnt_s[8];
        __shared__ int cplane_s[16], cbase_s[16];
        __shared__ int nch_s;
        int wave = tid >> 6, lane = tid & 63;
        for (int pp = wave; pp < 8; pp += 4) {
            int base = 0;
            for (int c0 = 0; c0 < NW_; c0 += 64) {
                int w = c0 + lane;
                bool hit = (a.plane_idx[w] == pp);
                unsigned long long mask = __ballot(hit);
                if (hit) {
                    int rank = __popcll(mask & ((1ull << lane) - 1ull));
                    a.plane_order[pp * NW_ + base + rank] = w;
                }
                base += __popcll(mask);
            }
            if (lane == 0) cnt_s[pp] = base;
        }
        __syncthreads();
        if (tid == 0) {
            int nc = 0;
            for (int p = 0; p < 8; ++p)
                for (int s0 = 0; s0 < cnt_s[p]; s0 += 32) {
                    cplane_s[nc] = p; cbase_s[nc] = s0; ++nc;
                }
            *a.nchunks = nc;
            nch_s = nc;
        }
        __syncthreads();
        int nc = nch_s;
        for (int idx = tid; idx < 512; idx += 256) {
            int c = idx >> 5, i = idx & 31;
            int v = -1;
            if (c < nc) {
                int p = cplane_s[c];
                int r = cbase_s[c] + i;
                if (r < cnt_s[p]) v = a.plane_order[p * NW_ + r];
            }
            a.chunk_rows[c * 32 + i] = v;
            if (v >= 0) a.slot_of[v] = c * 32 + i;
            if (i == 0) a.chunk_plane[c] = (c < nc) ? cplane_s[c] : 0;
        }
    } else {
        // s / ws restore copy
        int gid = (bid - 1025) * 256 + tid, stride = 2048 * 256;
        float4* s4o = reinterpret_cast<float4*>(a.out_s);
        const float4* s4i = reinterpret_cast<const float4*>(a.s_in);
        for (int i = gid; i < 4194304; i += stride) s4o[i] = s4i[i];
        float4* w4o = reinterpret_cast<float4*>(a.out_ws);
        const float4* w4i = reinterpret_cast<const float4*>(a.ws_in);
        for (int i = gid; i < 16384; i += stride) w4o[i] = w4i[i];
    }
}

// ---------------- steer body ----------------

__device__ void dev_steer(const KArgs& a, int w, int tid, int t) {
    int b = w >> 4;
    int p = a.pos[w];
    int slot = a.slot_of[w];
    float sc = a.out_s[((size_t)b * N_ + p) * DS_ + tid];
    float v = sc * sc;
    for (int off = 32; off > 0; off >>= 1) v += __shfl_down(v, off);
    __shared__ float red[4];
    if ((tid & 63) == 0) red[tid >> 6] = v;
    __syncthreads();
    float tot = red[0] + red[1] + red[2] + red[3];
    float r = rsqrtf(tot * (1.0f / DS_) + 1e-6f);
    float* st = a.steer + (size_t)w * DSTEER_;
    float v0 = sc * r * a.norm_w[tid];
    float v2 = a.out_ws[(size_t)w * DS_ + tid];
    float v3 = a.token[((size_t)b * T_ + t) * DS_ + tid];
    st[tid] = v0;
    st[384 + tid] = v2;
    st[640 + tid] = v3;
    a.steerT[(size_t)tid * SLOTS_ + slot] = v0;
    a.steerT[(size_t)(384 + tid) * SLOTS_ + slot] = v2;
    a.steerT[(size_t)(640 + tid) * SLOTS_ + slot] = v3;
    if (tid < 128) {
        float v1 = a.node_id[(size_t)p * DID_ + tid];
        st[256 + tid] = v1;
        a.steerT[(size_t)(256 + tid) * SLOTS_ + slot] = v1;
    }
}

// ---------------- setup2: keysB (512) + steer(0) (256) ----------------

__global__ __launch_bounds__(256) void setup2_kernel(KArgs a)
{
    int bid = blockIdx.x, tid = threadIdx.x;
    if (bid < 512) {
        int rt = bid >> 2, ct = bid & 3;
        int tr = tid >> 4, tc = tid & 15;
        int row = rt * 32 + tr * 2, col = ct * 64 + tc * 4;
        const float* a0 = a.kh + (size_t)row * QH_;
        float4 c0 = {0.f,0.f,0.f,0.f}, c1 = {0.f,0.f,0.f,0.f};
        rgemm_inner(a0, a0 + QH_, a.kw2 + col, QO_, QH_, c0, c1);
        float4 bv = *reinterpret_cast<const float4*>(a.kb2 + col);
        c0.x += bv.x; c0.y += bv.y; c0.z += bv.z; c0.w += bv.w;
        c1.x += bv.x; c1.y += bv.y; c1.z += bv.z; c1.w += bv.w;
        *reinterpret_cast<float4*>(a.keys + (size_t)row * QO_ + col) = c0;
        *reinterpret_cast<float4*>(a.keys + (size_t)(row + 1) * QO_ + col) = c1;
    } else {
        dev_steer(a, bid - 512, tid, 0);
    }
}

__global__ __launch_bounds__(256) void steer_kernel(KArgs a, int t)
{
    dev_steer(a, blockIdx.x, threadIdx.x, t);
}

// ---------------- layer1: K-split x4, LDS-staged B ----------------
// blocks 0..255:   q hidden (64r x 32c tiles, K=224): rt(4) x ct(16) x kp(4)
// blocks 256..1279: content hidden (64J x 32slot, K=224): c(16) x jt(16) x kp(4)

__global__ __launch_bounds__(256) void l1_kernel(KArgs a)
{
    __shared__ float bs[224 * 32];           // 28.7 KB
    int bid = blockIdx.x, tid = threadIdx.x;
    int tr = tid >> 3, tc = tid & 7;         // 32 x 8 threads: 2r x 4c each
    float4 c0 = {0.f,0.f,0.f,0.f}, c1 = {0.f,0.f,0.f,0.f};
    if (bid < 256) {
        int kp = bid & 3, tile = bid >> 2;   // 64 tiles: rt(4) x ct(16)
        int rt = tile >> 4, ct = tile & 15;
        int row = rt * 64 + tr * 2, col0 = ct * 32;
        // stage B = qw1[kp*224..+224][col0..+32]  (1792 float4s, 7 iters)
#pragma unroll
        for (int i = 0; i < 7; ++i) {
            int idx = tid + i * 256;
            int kk = idx >> 3, c4 = (idx & 7) << 2;
            *reinterpret_cast<float4*>(bs + kk * 32 + c4) =
                *reinterpret_cast<const float4*>(a.qw1 + (size_t)(kp * 224 + kk) * QH_ + col0 + c4);
        }
        __syncthreads();
        const float* a0 = a.steer + (size_t)row * DSTEER_ + kp * 224;
        rgemm_inner(a0, a0 + DSTEER_, bs + tc * 4, 32, 224, c0, c1);
        float* o = a.q1p + (size_t)kp * 131072;
        int col = col0 + tc * 4;
        *reinterpret_cast<float4*>(o + (size_t)row * QH_ + col) = c0;
        *reinterpret_cast<float4*>(o + (size_t)(row + 1) * QH_ + col) = c1;
    } else {
        int b2 = bid - 256;
        int kp = b2 & 3, tile = b2 >> 2;     // 256 tiles: c(16) x jt(16)
        int c = tile >> 4, jt = tile & 15;
        if (c >= *a.nchunks) return;
        int p = a.chunk_plane[c];
        int J = jt * 64 + tr * 2;
        // stage B = steerT[kp*224..+224][c*32..+32]  (1792 float4s)
#pragma unroll
        for (int i = 0; i < 7; ++i) {
            int idx = tid + i * 256;
            int kk = idx >> 3, s4 = (idx & 7) << 2;
            *reinterpret_cast<float4*>(bs + kk * 32 + s4) =
                *reinterpret_cast<const float4*>(a.steerT + (size_t)(kp * 224 + kk) * SLOTS_ + c * 32 + s4);
        }
        __syncthreads();
        const float* a0 = a.W1 + ((size_t)p * DHID_ + J) * DSTEER_ + kp * 224;
        rgemm_inner(a0, a0 + DSTEER_, bs + tc * 4, 32, 224, c0, c1);
        float* o = a.h1p + (size_t)kp * 524288;
        int slot = c * 32 + tc * 4;
        *reinterpret_cast<float4*>(o + (size_t)J * SLOTS_ + slot) = c0;
        *reinterpret_cast<float4*>(o + (size_t)(J + 1) * SLOTS_ + slot) = c1;
    }
}

// ---------------- layer2 fused ----------------
// blocks 0..255: q out (stage A from 4 q1p partials); 256..767: content out
// (stage B from 4 h1p partials). Content writes c2p TRANSPOSED [kp][slot][J].

__global__ __launch_bounds__(256) void l2f_kernel(KArgs a)
{
    __shared__ float smem[4096];             // 16 KB
    int bid = blockIdx.x, tid = threadIdx.x;
    if (bid < 256) {
        int kp = bid & 7, tile = bid >> 3;
        int rt = tile >> 2, ct = tile & 3;
        int tr = tid >> 4, tc = tid & 15;
        int row0 = rt * 32, col = ct * 64 + tc * 4;
        float4 c0 = {0.f,0.f,0.f,0.f}, c1 = {0.f,0.f,0.f,0.f};
        // stage A[32][64] (pad 72): A[r][k] = gelu(qb1 + sum_4 q1p)
#pragma unroll
        for (int i = 0; i < 2; ++i) {
            int idx = tid + i * 256;             // 512 float4s
            int r = idx >> 4, k4 = (idx & 15) << 2;
            size_t off = (size_t)(row0 + r) * QH_ + kp * 64 + k4;
            float4 acc = *reinterpret_cast<const float4*>(a.qb1 + kp * 64 + k4);
#pragma unroll
            for (int p4 = 0; p4 < 4; ++p4) {
                float4 v = *reinterpret_cast<const float4*>(a.q1p + (size_t)p4 * 131072 + off);
                acc.x += v.x; acc.y += v.y; acc.z += v.z; acc.w += v.w;
            }
            gelu4(acc);
            *reinterpret_cast<float4*>(smem + r * 72 + k4) = acc;
        }
        __syncthreads();
        const float* a0 = smem + (tr * 2) * 72;
        rgemm_inner(a0, a0 + 72, a.qw2 + (size_t)(kp * 64) * QO_ + col, QO_, 64, c0, c1);
        float* o = a.q2p + (size_t)kp * 65536;
        int row = row0 + tr * 2;
        *reinterpret_cast<float4*>(o + (size_t)row * QO_ + col) = c0;
        *reinterpret_cast<float4*>(o + (size_t)(row + 1) * QO_ + col) = c1;
    } else {
        int b2i = bid - 256;
        int kp = b2i & 7, tile = b2i >> 3;
        int c = tile >> 2, jt = tile & 3;
        if (c >= *a.nchunks) return;
        int p = a.chunk_plane[c];
        int tr = tid >> 3, tc = tid & 7;
        int J = jt * 64 + tr * 2;
        float4 c0 = {0.f,0.f,0.f,0.f}, c1 = {0.f,0.f,0.f,0.f};
        // stage B[128][32]: B[kk][s] = gelu(b1[p][kq] + sum_4 h1p)
#pragma unroll
        for (int i = 0; i < 4; ++i) {
            int idx = tid + i * 256;             // 1024 float4s
            int kk = idx >> 3, s4 = (idx & 7) << 2;
            int kq = kp * 128 + kk;
            size_t off = (size_t)kq * SLOTS_ + c * 32 + s4;
            float bj = a.b1[p * DHID_ + kq];
            float4 acc = {bj, bj, bj, bj};
#pragma unroll
            for (int p4 = 0; p4 < 4; ++p4) {
                float4 v = *reinterpret_cast<const float4*>(a.h1p + (size_t)p4 * 524288 + off);
                acc.x += v.x; acc.y += v.y; acc.z += v.z; acc.w += v.w;
            }
            gelu4(acc);
            *reinterpret_cast<float4*>(smem + kk * 32 + s4) = acc;
        }
        __syncthreads();
        const float* a0 = a.W2 + ((size_t)p * DS_ + J) * DHID_ + kp * 128;
        rgemm_inner(a0, a0 + DHID_, smem + tc * 4, 32, 128, c0, c1);
        // bounce acc through LDS -> write c2p transposed [slot][J] coalesced
        __syncthreads();
        int jl = tr * 2;
        smem[(tc*4+0)*66 + jl]     = c0.x;
        smem[(tc*4+1)*66 + jl]     = c0.y;
        smem[(tc*4+2)*66 + jl]     = c0.z;
        smem[(tc*4+3)*66 + jl]     = c0.w;
        smem[(tc*4+0)*66 + jl + 1] = c1.x;
        smem[(tc*4+1)*66 + jl + 1] = c1.y;
        smem[(tc*4+2)*66 + jl + 1] = c1.z;
        smem[(tc*4+3)*66 + jl + 1] = c1.w;
        __syncthreads();
        float* o = a.c2p + (size_t)kp * 131072;
#pragma unroll
        for (int i = 0; i < 2; ++i) {
            int f4i = tid + i * 256;     // 512 f4s: 32 slots x 16 f4-of-J
            int sl = f4i >> 4, j4 = (f4i & 15) << 2;
            float4 v;
            v.x = smem[sl * 66 + j4 + 0];
            v.y = smem[sl * 66 + j4 + 1];
            v.z = smem[sl * 66 + j4 + 2];
            v.w = smem[sl * 66 + j4 + 3];
            *reinterpret_cast<float4*>(o + (size_t)(c * 32 + sl) * 256 + jt * 64 + j4) = v;
        }
    }
}

// ---------------- score: sum l2 partials, softmax/argmax, state updates -----

__global__ __launch_bounds__(256) void score_kernel(KArgs a, int t)
{
    int w = blockIdx.x;
    int b = w >> 4;
    int tid = threadIdx.x;
    int pold = a.pos[w];
    int slot = a.slot_of[w];
    __shared__ float qv_s[256];
    __shared__ int nbr_s[32];
    __shared__ float part_s[8][32];
    __shared__ float sc_s[32];
    if (tid < 32) nbr_s[tid] = a.neighbors[(size_t)pold * K_ + tid];
    float qsum = a.qb2[tid];
#pragma unroll
    for (int kp = 0; kp < 8; ++kp) qsum += a.q2p[(size_t)kp * 65536 + (size_t)w * QO_ + tid];
    qv_s[tid] = qsum;
    // c2p transposed: [kp][slot][J] -> coalesced row read
    float csum = a.b2[a.chunk_plane[slot >> 5] * DS_ + tid];
#pragma unroll
    for (int kp = 0; kp < 8; ++kp) csum += a.c2p[(size_t)kp * 131072 + (size_t)slot * 256 + tid];
    __syncthreads();
    int k = tid & 31, part = tid >> 5;
    int nk = nbr_s[k];
    const float* kp_ = a.keys + (size_t)nk * 256 + part * 32;
    const float* qp = qv_s + part * 32;
    float acc = 0.f;
#pragma unroll
    for (int i = 0; i < 32; i += 4) {
        float4 kv = *reinterpret_cast<const float4*>(kp_ + i);
        acc += kv.x * qp[i] + kv.y * qp[i+1] + kv.z * qp[i+2] + kv.w * qp[i+3];
    }
    part_s[part][k] = acc;
    __syncthreads();
    if (tid < 32) {
        float s = 0.f;
#pragma unroll
        for (int p8 = 0; p8 < 8; ++p8) s += part_s[p8][tid];
        sc_s[tid] = s * SCORE_SCALE;
    }
    __syncthreads();
    if (tid < 32) {
        float sv = sc_s[tid];
        float m = sv;
        for (int off = 1; off < 32; off <<= 1) m = fmaxf(m, __shfl_xor(m, off));
        float e = expf(sv - m);
        float ssum = e;
        for (int off = 1; off < 32; off <<= 1) ssum += __shfl_xor(ssum, off);
        float prob = e / ssum;
        atomicAdd(&a.mp_all[t * 32 + tid], prob);
        float bs = sv; int bi = tid;
        for (int off = 1; off < 32; off <<= 1) {
            float os = __shfl_xor(bs, off);
            int   oi = __shfl_xor(bi, off);
            if (os > bs || (os == bs && oi < bi)) { bs = os; bi = oi; }
        }
        if (tid == 0) {
            int next = nbr_s[bi];
            a.pos[w] = next;
            if (t == T_ - 1) a.out_pos[w] = (float)next;
            atomicAdd(&a.out_co[(size_t)pold * N_ + next], 1.0f);
            atomicAdd(&a.out_vc[next], 1.0f);
        }
    }
    atomicAdd(&a.out_s[((size_t)b * N_ + pold) * DS_ + tid], csum);
    float wn = a.out_ws[(size_t)w * DS_ + tid] + csum;
    a.out_ws[(size_t)w * DS_ + tid] = wn;
    atomicAdd(&a.out_motor[((size_t)b * T_ + t) * DS_ + tid], wn * (1.0f / H_));
}

__global__ __launch_bounds__(256) void final_kernel(KArgs a)
{
    int tid = threadIdx.x;
    float v = a.mp_all[tid] * (1.0f / 256.f);
    v = v * v;
    for (int off = 32; off > 0; off >>= 1) v += __shfl_down(v, off);
    __shared__ float red[4];
    if ((tid & 63) == 0) red[tid >> 6] = v;
    __syncthreads();
    if (tid == 0) a.out_lb[0] = (float)K_ * (red[0] + red[1] + red[2] + red[3]);
}

// ---------------- launch ----------------

extern "C" void kernel_launch(void* const* d_in, const int* in_sizes, int n_in,
                              void* d_out, int out_size, void* d_ws, size_t ws_size,
                              hipStream_t stream)
{
    KArgs a;
    a.s_in    = (const float*)d_in[0];
    a.node_id = (const float*)d_in[1];
    a.ws_in   = (const float*)d_in[2];
    a.token   = (const float*)d_in[3];
    a.norm_w  = (const float*)d_in[4];
    a.W1  = (const float*)d_in[5];
    a.b1  = (const float*)d_in[6];
    a.W2  = (const float*)d_in[7];
    a.b2  = (const float*)d_in[8];
    a.qw1 = (const float*)d_in[9];
    a.qb1 = (const float*)d_in[10];
    a.qw2 = (const float*)d_in[11];
    a.qb2 = (const float*)d_in[12];
    a.kw1 = (const float*)d_in[13];
    a.kb1 = (const float*)d_in[14];
    a.kw2 = (const float*)d_in[15];
    a.kb2 = (const float*)d_in[16];
    a.walker_pos = (const int*)d_in[17];
    a.plane_idx  = (const int*)d_in[18];
    a.neighbors  = (const int*)d_in[19];

    float* out = (float*)d_out;
    a.out_motor = out;                               // 32768
    a.out_s     = a.out_motor + 32768;               // 16777216
    a.out_pos   = a.out_s + (size_t)16777216;        // 256
    a.out_ws    = a.out_pos + 256;                   // 65536
    a.out_co    = a.out_ws + 65536;                  // 16777216
    a.out_vc    = a.out_co + (size_t)16777216;       // 4096
    a.out_lb    = a.out_vc + 4096;                   // 1

    float* ws = (float*)d_ws;
    a.keys   = ws;                                   // 1,048,576
    a.steer  = a.keys + 1048576;                     // 229,376
    a.steerT = a.steer + 229376;                     // 458,752
    a.h1p    = a.steerT + 458752;                    // 2,097,152 (4 partials)
    a.kh     = a.h1p;                                // alias (setup only, 2,097,152)
    a.q1p    = a.h1p + 2097152;                      // 524,288 (4 partials)
    a.c2p    = a.q1p + 524288;                       // 1,048,576 (transposed, 8)
    a.q2p    = a.c2p + 1048576;                      // 524,288 (8 partials)
    a.mp_all = a.q2p + 524288;                       // 256
    a.pos         = (int*)(a.mp_all + 256);          // 256
    a.plane_order = a.pos + 256;                     // 2048
    a.chunk_plane = a.plane_order + 2048;            // 16
    a.chunk_rows  = a.chunk_plane + 16;              // 512
    a.slot_of     = a.chunk_rows + 512;              // 256
    a.nchunks     = a.slot_of + 256;                 // 1

    // zero outputs via runtime fill path (~6.9 TB/s measured on this chip)
    hipMemsetAsync(a.out_motor, 0, 32768 * sizeof(float), stream);
    hipMemsetAsync(a.out_co, 0, (size_t)(16777216 + 4096 + 1) * sizeof(float), stream);

    setup1_kernel<<<1024 + 1 + 2048, 256, 0, stream>>>(a);
    setup2_kernel<<<512 + 256, 256, 0, stream>>>(a);
    for (int t = 0; t < T_; ++t) {
        l1_kernel<<<256 + 1024, 256, 0, stream>>>(a);
        l2f_kernel<<<768, 256, 0, stream>>>(a);
        score_kernel<<<256, 256, 0, stream>>>(a, t);
        if (t < T_ - 1) steer_kernel<<<256, 256, 0, stream>>>(a, t + 1);
    }
    final_kernel<<<1, 256, 0, stream>>>(a);
}

// Round 14
// 485.930 us; speedup vs baseline: 1.2972x; 1.0335x over previous
//
#include <hip/hip_runtime.h>
#include <math.h>

#define B_    16
#define H_    16
#define N_    4096
#define T_    8
#define DS_   256
#define DID_  128
#define L_    8
#define K_    32
#define DHID_ 1024
#define DSTEER_ 896
#define QH_   512
#define QO_   256
#define NW_   256   // B*H walkers
#define SLOTS_ 512  // chunk-slot space: 16 chunks x 32 slots
#define BSLD_ 36    // LDS B-tile row pad (conflict-free b128 reads, ~4-way stores)
#define SCORE_SCALE 0.022097086912079608f  // 1/(8*sqrt(32))

struct KArgs {
    const float *s_in, *node_id, *ws_in, *token, *norm_w;
    const float *W1, *b1, *W2, *b2;
    const float *qw1, *qb1, *qw2, *qb2, *kw1, *kb1, *kw2, *kb2;
    const int *walker_pos, *plane_idx, *neighbors;
    float *out_motor, *out_s, *out_pos, *out_ws, *out_co, *out_vc, *out_lb;
    float *keys, *kh, *qw1T, *qw2T, *h1p, *q1p, *c2p, *q2p, *mp_all;
    int *pos, *plane_order, *chunk_plane, *chunk_rows, *slot_of, *nchunks;
};

__device__ __forceinline__ float gelu_exact(float x) {
    return 0.5f * x * (1.0f + erff(x * 0.70710678118654752f));
}

#define FMA4(c, b, a) { c.x = fmaf(b.x, (a), c.x); c.y = fmaf(b.y, (a), c.y); \
                        c.z = fmaf(b.z, (a), c.z); c.w = fmaf(b.w, (a), c.w); }

__device__ __forceinline__ void gelu4(float4& v) {
    v.x = gelu_exact(v.x); v.y = gelu_exact(v.y);
    v.z = gelu_exact(v.z); v.w = gelu_exact(v.w);
}

// 2-row x 4-col register tile; A from global, B in LDS (row stride ldb).
__device__ __forceinline__ void rgemm_inner(
    const float* __restrict__ a0, const float* __restrict__ a1,
    const float* bp, int ldb, int K,
    float4& c0, float4& c1)
{
    for (int k = 0; k < K; k += 8) {
        const float4 a0l = *reinterpret_cast<const float4*>(a0 + k);
        const float4 a0h = *reinterpret_cast<const float4*>(a0 + k + 4);
        const float4 a1l = *reinterpret_cast<const float4*>(a1 + k);
        const float4 a1h = *reinterpret_cast<const float4*>(a1 + k + 4);
        const float* b8 = bp + (size_t)k * ldb;
#define KSTEP(o, av0, av1) { float4 bv = *reinterpret_cast<const float4*>(b8 + (size_t)(o) * ldb); \
                             FMA4(c0, bv, av0); FMA4(c1, bv, av1); }
        KSTEP(0, a0l.x, a1l.x)
        KSTEP(1, a0l.y, a1l.y)
        KSTEP(2, a0l.z, a1l.z)
        KSTEP(3, a0l.w, a1l.w)
        KSTEP(4, a0h.x, a1h.x)
        KSTEP(5, a0h.y, a1h.y)
        KSTEP(6, a0h.z, a1h.z)
        KSTEP(7, a0h.w, a1h.w)
#undef KSTEP
    }
}

// ---- setup1: keysA (0..1023) + tables (1024) + qw1T/qw2T transpose
//      (1025..1600) + s/ws copy (1601..3648) --------------------------------

__global__ __launch_bounds__(256) void setup1_kernel(KArgs a)
{
    int bid = blockIdx.x, tid = threadIdx.x;
    if (bid < 1024) {
        // keysA: kh = gelu(node_id @ kw1 + kb1)
        int u = bid;
        int rt = u >> 3, ct = u & 7;
        int tr = tid >> 4, tc = tid & 15;
        int row = rt * 32 + tr * 2, col = ct * 64 + tc * 4;
        const float* a0 = a.node_id + (size_t)row * DID_;
        // kw1 is d-major [128][512]; stream B directly from global (K small)
        float4 c0 = {0.f,0.f,0.f,0.f}, c1 = {0.f,0.f,0.f,0.f};
        rgemm_inner(a0, a0 + DID_, a.kw1 + col, QH_, DID_, c0, c1);
        float4 bv = *reinterpret_cast<const float4*>(a.kb1 + col);
        c0.x += bv.x; c0.y += bv.y; c0.z += bv.z; c0.w += bv.w;
        c1.x += bv.x; c1.y += bv.y; c1.z += bv.z; c1.w += bv.w;
        gelu4(c0); gelu4(c1);
        *reinterpret_cast<float4*>(a.kh + (size_t)row * QH_ + col) = c0;
        *reinterpret_cast<float4*>(a.kh + (size_t)(row + 1) * QH_ + col) = c1;
    } else if (bid == 1024) {
        a.pos[tid] = a.walker_pos[tid];
        a.mp_all[tid] = 0.f;
        __shared__ int cnt_s[8];
        __shared__ int cplane_s[16], cbase_s[16];
        __shared__ int nch_s;
        int wave = tid >> 6, lane = tid & 63;
        for (int pp = wave; pp < 8; pp += 4) {
            int base = 0;
            for (int c0 = 0; c0 < NW_; c0 += 64) {
                int w = c0 + lane;
                bool hit = (a.plane_idx[w] == pp);
                unsigned long long mask = __ballot(hit);
                if (hit) {
                    int rank = __popcll(mask & ((1ull << lane) - 1ull));
                    a.plane_order[pp * NW_ + base + rank] = w;
                }
                base += __popcll(mask);
            }
            if (lane == 0) cnt_s[pp] = base;
        }
        __syncthreads();
        if (tid == 0) {
            int nc = 0;
            for (int p = 0; p < 8; ++p)
                for (int s0 = 0; s0 < cnt_s[p]; s0 += 32) {
                    cplane_s[nc] = p; cbase_s[nc] = s0; ++nc;
                }
            *a.nchunks = nc;
            nch_s = nc;
        }
        __syncthreads();
        int nc = nch_s;
        for (int idx = tid; idx < 512; idx += 256) {
            int c = idx >> 5, i = idx & 31;
            int v = -1;
            if (c < nc) {
                int p = cplane_s[c];
                int r = cbase_s[c] + i;
                if (r < cnt_s[p]) v = a.plane_order[p * NW_ + r];
            }
            a.chunk_rows[c * 32 + i] = v;
            if (v >= 0) a.slot_of[v] = c * 32 + i;
            if (i == 0) a.chunk_plane[c] = (c < nc) ? cplane_s[c] : 0;
        }
    } else if (bid < 1601) {
        // weight transposes via 32x32 LDS tiles
        __shared__ float ts[32][33];
        int u = bid - 1025;
        const float* src; float* dst; int srcld, dstld, td, tj;
        if (u < 448) {              // qw1 [896][512] -> qw1T [512][896]
            src = a.qw1; dst = a.qw1T; srcld = QH_; dstld = DSTEER_;
            td = u >> 4; tj = u & 15;
        } else {                    // qw2 [512][256] -> qw2T [256][512]
            u -= 448;               // 128 blocks
            src = a.qw2; dst = a.qw2T; srcld = QO_; dstld = QH_;
            td = u >> 3; tj = u & 7;
        }
#pragma unroll
        for (int i = 0; i < 4; ++i) {
            int e = tid + i * 256;
            int r = e >> 5, cc = e & 31;
            ts[r][cc] = src[(size_t)(td * 32 + r) * srcld + tj * 32 + cc];
        }
        __syncthreads();
#pragma unroll
        for (int i = 0; i < 4; ++i) {
            int e = tid + i * 256;
            int r = e >> 5, cc = e & 31;
            dst[(size_t)(tj * 32 + r) * dstld + td * 32 + cc] = ts[cc][r];
        }
    } else {
        // s / ws restore copy
        int gid = (bid - 1601) * 256 + tid, stride = 2048 * 256;
        float4* s4o = reinterpret_cast<float4*>(a.out_s);
        const float4* s4i = reinterpret_cast<const float4*>(a.s_in);
        for (int i = gid; i < 4194304; i += stride) s4o[i] = s4i[i];
        float4* w4o = reinterpret_cast<float4*>(a.out_ws);
        const float4* w4i = reinterpret_cast<const float4*>(a.ws_in);
        for (int i = gid; i < 16384; i += stride) w4o[i] = w4i[i];
    }
}

// ---------------- setup2: keysB (512 blocks) ----------------

__global__ __launch_bounds__(256) void setup2_kernel(KArgs a)
{
    int bid = blockIdx.x, tid = threadIdx.x;
    int rt = bid >> 2, ct = bid & 3;
    int tr = tid >> 4, tc = tid & 15;
    int row = rt * 32 + tr * 2, col = ct * 64 + tc * 4;
    const float* a0 = a.kh + (size_t)row * QH_;
    float4 c0 = {0.f,0.f,0.f,0.f}, c1 = {0.f,0.f,0.f,0.f};
    rgemm_inner(a0, a0 + QH_, a.kw2 + col, QO_, QH_, c0, c1);
    float4 bv = *reinterpret_cast<const float4*>(a.kb2 + col);
    c0.x += bv.x; c0.y += bv.y; c0.z += bv.z; c0.w += bv.w;
    c1.x += bv.x; c1.y += bv.y; c1.z += bv.z; c1.w += bv.w;
    *reinterpret_cast<float4*>(a.keys + (size_t)row * QO_ + col) = c0;
    *reinterpret_cast<float4*>(a.keys + (size_t)(row + 1) * QO_ + col) = c1;
}

// ---------------- layer1 with fused steer staging ----------------
// blocks 0..255:   q hidden: wt(8: 32 walkers) x jt(8: 64 j) x kp(4), K=224
// blocks 256..1279: content hidden: c(16) x jt(16: 64 J) x kp(4), K=224
// Each block stages its own steer-slice B[224][32] in LDS from
// (pos, out_s, out_ws, node_id, token) with on-the-fly RMS norm.

__global__ __launch_bounds__(256) void l1_kernel(KArgs a, int t)
{
    __shared__ float bs[224 * BSLD_];        // 32.25 KB
    __shared__ float rms_s[32];
    __shared__ int w_s[32], pos_s[32];
    int bid = blockIdx.x, tid = threadIdx.x;
    int kp, jt, c = -1, p = 0, wt = 0, isQ;
    if (bid < 256) {
        isQ = 1; kp = bid & 3;
        int tile = bid >> 2;                 // 64: wt(8) x jt(8)
        wt = tile >> 3; jt = tile & 7;
    } else {
        isQ = 0;
        int b2 = bid - 256; kp = b2 & 3;
        int tile = b2 >> 2;                  // 256: c(16) x jt(16)
        c = tile >> 4; jt = tile & 15;
        if (c >= *a.nchunks) return;
        p = a.chunk_plane[c];
    }
    int g = tid >> 3, l8 = tid & 7;          // g: walker column, l8: k-chunk
    if (l8 == 0) {
        int w = isQ ? (wt * 32 + g) : a.chunk_rows[c * 32 + g];
        w_s[g] = w;
        pos_s[g] = (w >= 0) ? a.pos[w] : 0;
    }
    __syncthreads();
    if (kp < 2) {                            // rms only needed when slice hits s_n
        int w = w_s[g];
        float ssum = 0.f;
        if (w >= 0) {
            const float* sr = a.out_s + ((size_t)(w >> 4) * N_ + pos_s[g]) * DS_ + l8 * 32;
#pragma unroll
            for (int i = 0; i < 8; ++i) {
                float4 v = *reinterpret_cast<const float4*>(sr + i * 4);
                ssum += v.x * v.x + v.y * v.y + v.z * v.z + v.w * v.w;
            }
        }
        ssum += __shfl_xor(ssum, 1);
        ssum += __shfl_xor(ssum, 2);
        ssum += __shfl_xor(ssum, 4);
        if (l8 == 0) rms_s[g] = rsqrtf(ssum * (1.0f / DS_) + 1e-6f);
    }
    __syncthreads();
    {   // stage B: column g, elems kk = l8*28 .. +28
        int w = w_s[g];
        int b = (w >= 0) ? (w >> 4) : 0;
        int pp = pos_s[g];
        float rr = (kp < 2) ? rms_s[g] : 0.f;
#pragma unroll
        for (int i = 0; i < 7; ++i) {
            int kk = l8 * 28 + i * 4;
            int d4 = kp * 224 + kk;
            float4 v = make_float4(0.f, 0.f, 0.f, 0.f);
            if (w >= 0) {
                if (d4 < 256) {
                    float4 sv = *reinterpret_cast<const float4*>(
                        a.out_s + ((size_t)b * N_ + pp) * DS_ + d4);
                    float4 nv = *reinterpret_cast<const float4*>(a.norm_w + d4);
                    v.x = sv.x * rr * nv.x; v.y = sv.y * rr * nv.y;
                    v.z = sv.z * rr * nv.z; v.w = sv.w * rr * nv.w;
                } else if (d4 < 384) {
                    v = *reinterpret_cast<const float4*>(
                        a.node_id + (size_t)pp * DID_ + (d4 - 256));
                } else if (d4 < 640) {
                    v = *reinterpret_cast<const float4*>(
                        a.out_ws + (size_t)w * DS_ + (d4 - 384));
                } else {
                    v = *reinterpret_cast<const float4*>(
                        a.token + ((size_t)b * T_ + t) * DS_ + (d4 - 640));
                }
            }
            bs[(kk + 0) * BSLD_ + g] = v.x;
            bs[(kk + 1) * BSLD_ + g] = v.y;
            bs[(kk + 2) * BSLD_ + g] = v.z;
            bs[(kk + 3) * BSLD_ + g] = v.w;
        }
    }
    __syncthreads();
    int tr = tid >> 3, tc = tid & 7;
    float4 c0 = {0.f,0.f,0.f,0.f}, c1 = {0.f,0.f,0.f,0.f};
    if (isQ) {
        int j = jt * 64 + tr * 2;
        const float* a0 = a.qw1T + (size_t)j * DSTEER_ + kp * 224;
        rgemm_inner(a0, a0 + DSTEER_, bs + tc * 4, BSLD_, 224, c0, c1);
        float* o = a.q1p + (size_t)kp * 131072;  // [512 j][256 w]
        int w4 = wt * 32 + tc * 4;
        *reinterpret_cast<float4*>(o + (size_t)j * NW_ + w4) = c0;
        *reinterpret_cast<float4*>(o + (size_t)(j + 1) * NW_ + w4) = c1;
    } else {
        int J = jt * 64 + tr * 2;
        const float* a0 = a.W1 + ((size_t)p * DHID_ + J) * DSTEER_ + kp * 224;
        rgemm_inner(a0, a0 + DSTEER_, bs + tc * 4, BSLD_, 224, c0, c1);
        float* o = a.h1p + (size_t)kp * 524288;  // [1024 J][512 slots]
        int slot = c * 32 + tc * 4;
        *reinterpret_cast<float4*>(o + (size_t)J * SLOTS_ + slot) = c0;
        *reinterpret_cast<float4*>(o + (size_t)(J + 1) * SLOTS_ + slot) = c1;
    }
}

// ---------------- layer2 fused (both paths transposed form) ----------------
// blocks 0..255: q out: colt(4) x wt(8) x kp(8: 64-h K-split); A = qw2T rows,
//   B = gelu(qb1 + sum_4 q1p) [64 h][32 w]; out q2p[kp][w][col] via bounce.
// blocks 256..767: content out: c(16) x jt(4) x kp(8: 128-K); A = W2 rows,
//   B = gelu(b1 + sum_4 h1p) [128][32]; out c2p[kp][slot][J] via bounce.

__global__ __launch_bounds__(256) void l2f_kernel(KArgs a)
{
    __shared__ float smem[4224];             // 16.5 KB
    int bid = blockIdx.x, tid = threadIdx.x;
    if (bid < 256) {
        int kp = bid & 7, tile = bid >> 3;   // 32: colt(4) x wt(8)
        int colt = tile >> 3, wt = tile & 7;
        // stage B[64 h][32 w]
#pragma unroll
        for (int i = 0; i < 8; ++i) {
            int idx = tid + i * 256;         // 2048
            int hh = idx >> 5, wl = idx & 31;
            size_t off = (size_t)(kp * 64 + hh) * NW_ + wt * 32 + wl;
            float acc = a.qb1[kp * 64 + hh];
#pragma unroll
            for (int p4 = 0; p4 < 4; ++p4) acc += a.q1p[(size_t)p4 * 131072 + off];
            smem[hh * 32 + wl] = gelu_exact(acc);
        }
        __syncthreads();
        int tr = tid >> 3, tc = tid & 7;
        int col = colt * 64 + tr * 2;
        const float* a0 = a.qw2T + (size_t)col * QH_ + kp * 64;
        float4 c0 = {0.f,0.f,0.f,0.f}, c1 = {0.f,0.f,0.f,0.f};
        rgemm_inner(a0, a0 + QH_, smem + tc * 4, 32, 64, c0, c1);
        // bounce: smem[wl][col-local] then coalesced write q2p[kp][w][col]
        __syncthreads();
        int cl = tr * 2;
        smem[(tc*4+0)*66 + cl]     = c0.x;
        smem[(tc*4+1)*66 + cl]     = c0.y;
        smem[(tc*4+2)*66 + cl]     = c0.z;
        smem[(tc*4+3)*66 + cl]     = c0.w;
        smem[(tc*4+0)*66 + cl + 1] = c1.x;
        smem[(tc*4+1)*66 + cl + 1] = c1.y;
        smem[(tc*4+2)*66 + cl + 1] = c1.z;
        smem[(tc*4+3)*66 + cl + 1] = c1.w;
        __syncthreads();
        float* o = a.q2p + (size_t)kp * 65536;   // [256 w][256 col]
#pragma unroll
        for (int i = 0; i < 2; ++i) {
            int f4i = tid + i * 256;         // 512: 32 wl x 16 f4
            int wl = f4i >> 4, j4 = (f4i & 15) << 2;
            float4 v;
            v.x = smem[wl * 66 + j4 + 0];
            v.y = smem[wl * 66 + j4 + 1];
            v.z = smem[wl * 66 + j4 + 2];
            v.w = smem[wl * 66 + j4 + 3];
            *reinterpret_cast<float4*>(o + (size_t)(wt * 32 + wl) * QO_ + colt * 64 + j4) = v;
        }
    } else {
        int b2i = bid - 256;
        int kp = b2i & 7, tile = b2i >> 3;
        int c = tile >> 2, jt = tile & 3;
        if (c >= *a.nchunks) return;
        int p = a.chunk_plane[c];
        int tr = tid >> 3, tc = tid & 7;
        int J = jt * 64 + tr * 2;
        float4 c0 = {0.f,0.f,0.f,0.f}, c1 = {0.f,0.f,0.f,0.f};
        // stage B[128][32]: gelu(b1[p][kq] + sum_4 h1p)
#pragma unroll
        for (int i = 0; i < 4; ++i) {
            int idx = tid + i * 256;         // 1024
            int kk = idx >> 3, s4 = (idx & 7) << 2;
            int kq = kp * 128 + kk;
            size_t off = (size_t)kq * SLOTS_ + c * 32 + s4;
            float bj = a.b1[p * DHID_ + kq];
            float4 acc = {bj, bj, bj, bj};
#pragma unroll
            for (int p4 = 0; p4 < 4; ++p4) {
                float4 v = *reinterpret_cast<const float4*>(a.h1p + (size_t)p4 * 524288 + off);
                acc.x += v.x; acc.y += v.y; acc.z += v.z; acc.w += v.w;
            }
            gelu4(acc);
            *reinterpret_cast<float4*>(smem + kk * 32 + s4) = acc;
        }
        __syncthreads();
        const float* a0 = a.W2 + ((size_t)p * DS_ + J) * DHID_ + kp * 128;
        rgemm_inner(a0, a0 + DHID_, smem + tc * 4, 32, 128, c0, c1);
        __syncthreads();
        int jl = tr * 2;
        smem[(tc*4+0)*66 + jl]     = c0.x;
        smem[(tc*4+1)*66 + jl]     = c0.y;
        smem[(tc*4+2)*66 + jl]     = c0.z;
        smem[(tc*4+3)*66 + jl]     = c0.w;
        smem[(tc*4+0)*66 + jl + 1] = c1.x;
        smem[(tc*4+1)*66 + jl + 1] = c1.y;
        smem[(tc*4+2)*66 + jl + 1] = c1.z;
        smem[(tc*4+3)*66 + jl + 1] = c1.w;
        __syncthreads();
        float* o = a.c2p + (size_t)kp * 131072;  // [512 slot][256 J]
#pragma unroll
        for (int i = 0; i < 2; ++i) {
            int f4i = tid + i * 256;
            int sl = f4i >> 4, j4 = (f4i & 15) << 2;
            float4 v;
            v.x = smem[sl * 66 + j4 + 0];
            v.y = smem[sl * 66 + j4 + 1];
            v.z = smem[sl * 66 + j4 + 2];
            v.w = smem[sl * 66 + j4 + 3];
            *reinterpret_cast<float4*>(o + (size_t)(c * 32 + sl) * 256 + jt * 64 + j4) = v;
        }
    }
}

// ---------------- score: sum l2 partials, softmax/argmax, state updates -----

__global__ __launch_bounds__(256) void score_kernel(KArgs a, int t)
{
    int w = blockIdx.x;
    int b = w >> 4;
    int tid = threadIdx.x;
    int pold = a.pos[w];
    int slot = a.slot_of[w];
    __shared__ float qv_s[256];
    __shared__ int nbr_s[32];
    __shared__ float part_s[8][32];
    __shared__ float sc_s[32];
    if (tid < 32) nbr_s[tid] = a.neighbors[(size_t)pold * K_ + tid];
    float qsum = a.qb2[tid];
#pragma unroll
    for (int kp = 0; kp < 8; ++kp) qsum += a.q2p[(size_t)kp * 65536 + (size_t)w * QO_ + tid];
    qv_s[tid] = qsum;
    float csum = a.b2[a.chunk_plane[slot >> 5] * DS_ + tid];
#pragma unroll
    for (int kp = 0; kp < 8; ++kp) csum += a.c2p[(size_t)kp * 131072 + (size_t)slot * 256 + tid];
    __syncthreads();
    int k = tid & 31, part = tid >> 5;
    int nk = nbr_s[k];
    const float* kp_ = a.keys + (size_t)nk * 256 + part * 32;
    const float* qp = qv_s + part * 32;
    float acc = 0.f;
#pragma unroll
    for (int i = 0; i < 32; i += 4) {
        float4 kv = *reinterpret_cast<const float4*>(kp_ + i);
        acc += kv.x * qp[i] + kv.y * qp[i+1] + kv.z * qp[i+2] + kv.w * qp[i+3];
    }
    part_s[part][k] = acc;
    __syncthreads();
    if (tid < 32) {
        float s = 0.f;
#pragma unroll
        for (int p8 = 0; p8 < 8; ++p8) s += part_s[p8][tid];
        sc_s[tid] = s * SCORE_SCALE;
    }
    __syncthreads();
    if (tid < 32) {
        float sv = sc_s[tid];
        float m = sv;
        for (int off = 1; off < 32; off <<= 1) m = fmaxf(m, __shfl_xor(m, off));
        float e = expf(sv - m);
        float ssum = e;
        for (int off = 1; off < 32; off <<= 1) ssum += __shfl_xor(ssum, off);
        float prob = e / ssum;
        atomicAdd(&a.mp_all[t * 32 + tid], prob);
        float bs = sv; int bi = tid;
        for (int off = 1; off < 32; off <<= 1) {
            float os = __shfl_xor(bs, off);
            int   oi = __shfl_xor(bi, off);
            if (os > bs || (os == bs && oi < bi)) { bs = os; bi = oi; }
        }
        if (tid == 0) {
            int next = nbr_s[bi];
            a.pos[w] = next;
            if (t == T_ - 1) a.out_pos[w] = (float)next;
            atomicAdd(&a.out_co[(size_t)pold * N_ + next], 1.0f);
            atomicAdd(&a.out_vc[next], 1.0f);
        }
    }
    atomicAdd(&a.out_s[((size_t)b * N_ + pold) * DS_ + tid], csum);
    float wn = a.out_ws[(size_t)w * DS_ + tid] + csum;
    a.out_ws[(size_t)w * DS_ + tid] = wn;
    atomicAdd(&a.out_motor[((size_t)b * T_ + t) * DS_ + tid], wn * (1.0f / H_));
}

__global__ __launch_bounds__(256) void final_kernel(KArgs a)
{
    int tid = threadIdx.x;
    float v = a.mp_all[tid] * (1.0f / 256.f);
    v = v * v;
    for (int off = 32; off > 0; off >>= 1) v += __shfl_down(v, off);
    __shared__ float red[4];
    if ((tid & 63) == 0) red[tid >> 6] = v;
    __syncthreads();
    if (tid == 0) a.out_lb[0] = (float)K_ * (red[0] + red[1] + red[2] + red[3]);
}

// ---------------- launch ----------------

extern "C" void kernel_launch(void* const* d_in, const int* in_sizes, int n_in,
                              void* d_out, int out_size, void* d_ws, size_t ws_size,
                              hipStream_t stream)
{
    KArgs a;
    a.s_in    = (const float*)d_in[0];
    a.node_id = (const float*)d_in[1];
    a.ws_in   = (const float*)d_in[2];
    a.token   = (const float*)d_in[3];
    a.norm_w  = (const float*)d_in[4];
    a.W1  = (const float*)d_in[5];
    a.b1  = (const float*)d_in[6];
    a.W2  = (const float*)d_in[7];
    a.b2  = (const float*)d_in[8];
    a.qw1 = (const float*)d_in[9];
    a.qb1 = (const float*)d_in[10];
    a.qw2 = (const float*)d_in[11];
    a.qb2 = (const float*)d_in[12];
    a.kw1 = (const float*)d_in[13];
    a.kb1 = (const float*)d_in[14];
    a.kw2 = (const float*)d_in[15];
    a.kb2 = (const float*)d_in[16];
    a.walker_pos = (const int*)d_in[17];
    a.plane_idx  = (const int*)d_in[18];
    a.neighbors  = (const int*)d_in[19];

    float* out = (float*)d_out;
    a.out_motor = out;                               // 32768
    a.out_s     = a.out_motor + 32768;               // 16777216
    a.out_pos   = a.out_s + (size_t)16777216;        // 256
    a.out_ws    = a.out_pos + 256;                   // 65536
    a.out_co    = a.out_ws + 65536;                  // 16777216
    a.out_vc    = a.out_co + (size_t)16777216;       // 4096
    a.out_lb    = a.out_vc + 4096;                   // 1

    float* ws = (float*)d_ws;
    a.keys   = ws;                                   // 1,048,576
    a.qw1T   = a.keys + 1048576;                     // 458,752
    a.qw2T   = a.qw1T + 458752;                      // 131,072
    a.h1p    = a.qw2T + 131072;                      // 2,097,152 (4 partials)
    a.kh     = a.h1p;                                // alias (setup only)
    a.q1p    = a.h1p + 2097152;                      // 524,288 (4 partials, [j][w])
    a.c2p    = a.q1p + 524288;                       // 1,048,576 (transposed, 8)
    a.q2p    = a.c2p + 1048576;                      // 524,288 (8 partials, [w][col])
    a.mp_all = a.q2p + 524288;                       // 256
    a.pos         = (int*)(a.mp_all + 256);          // 256
    a.plane_order = a.pos + 256;                     // 2048
    a.chunk_plane = a.plane_order + 2048;            // 16
    a.chunk_rows  = a.chunk_plane + 16;              // 512
    a.slot_of     = a.chunk_rows + 512;              // 256
    a.nchunks     = a.slot_of + 256;                 // 1

    // zero outputs via runtime fill path (~6.9 TB/s measured on this chip)
    hipMemsetAsync(a.out_motor, 0, 32768 * sizeof(float), stream);
    hipMemsetAsync(a.out_co, 0, (size_t)(16777216 + 4096 + 1) * sizeof(float), stream);

    setup1_kernel<<<1024 + 1 + 576 + 2048, 256, 0, stream>>>(a);
    setup2_kernel<<<512, 256, 0, stream>>>(a);
    for (int t = 0; t < T_; ++t) {
        l1_kernel<<<256 + 1024, 256, 0, stream>>>(a, t);
        l2f_kernel<<<768, 256, 0, stream>>>(a);
        score_kernel<<<256, 256, 0, stream>>>(a, t);
    }
    final_kernel<<<1, 256, 0, stream>>>(a);
}